// Round 4
// baseline (857.968 us; speedup 1.0000x reference)
//
#include <hip/hip_runtime.h>
#include <hip/hip_bf16.h>
#include <math.h>

// =============================================================================
// v4: conv1-4 = split-bf16 3-pass MFMA implicit-GEMM, now BARRIER-FREE and
//     LDS-FREE: both A (packed weight fragment image) and B (hi/lo bf16
//     activations) load directly from global memory as coalesced dwordx4.
//     One wave per block; wave tile = 48 rows x (NTW*16) cols; grid =
//     B x t-tiles x 2 row-halves. Occupancy is VGPR-bound only; no syncs.
// conv5-7 + pools + masked max + MLP head stay on the verified fp32 path.
// =============================================================================

typedef __attribute__((ext_vector_type(8))) short bf16x8;   // 8 bf16 in 4 VGPRs
typedef __attribute__((ext_vector_type(4))) float f32x4;

__device__ __forceinline__ unsigned int f2b(float f) {      // fp32 -> bf16 bits (RNE)
    unsigned int u = __float_as_uint(f);
    return (u + 0x7fffu + ((u >> 16) & 1u)) >> 16;
}
__device__ __forceinline__ float b2f(unsigned int h) { return __uint_as_float(h << 16); }

// ---------------------------------------------------------------------------
// A image layout (per K-step of 32): [step][half][mg(6)][lane(64)][j(8)] bf16;
// per-lane fragment is 16 contiguous bytes -> global_load_dwordx4.
// B frag: lane(quad q, l16) holds patch[k=q*8+j][t=tbase+16*nt] ->
// 4 consecutive dwords of the hi/lo activation rows.
// ---------------------------------------------------------------------------
template<int KP, int KW, int CI, int NTW, bool RELU, bool OUT_BF16>
__global__ __launch_bounds__(64)
void conv_mfma_g(const unsigned short* __restrict__ xh,
                 const unsigned short* __restrict__ xl,
                 const unsigned short* __restrict__ wpk,
                 const float* __restrict__ bias,
                 unsigned short* __restrict__ yh,
                 unsigned short* __restrict__ yl,
                 float* __restrict__ yf,
                 int Tin, int Tout)
{
    constexpr int CO    = 96;
    constexpr int STEPS = CI * KP / 32;
    constexpr int NB    = NTW * 16;

    const int lane = threadIdx.x;
    const int quad = lane >> 4;
    const int l16  = lane & 15;

    const int nT  = (Tout + NB - 1) / NB;
    int bid = blockIdx.x;
    const int wm   = bid & 1; bid >>= 1;
    const int tile = bid % nT;
    const int b    = bid / nT;
    const int t0   = tile * NB;

    const unsigned int* xbh = (const unsigned int*)(xh + (size_t)b * CI * Tin);
    const unsigned int* xbl = (const unsigned int*)(xl + (size_t)b * CI * Tin);
    const int tbase = t0 + l16;
    const int rowd  = Tin >> 1;          // dwords per channel row

    f32x4 acc[3][NTW];
    #pragma unroll
    for (int mt = 0; mt < 3; mt++)
        #pragma unroll
        for (int nt = 0; nt < NTW; nt++) acc[mt][nt] = (f32x4)0.f;

    for (int s = 0; s < STEPS; ++s) {
        // A fragments for this step (per-lane 16B, coalesced, L2-hot)
        const unsigned short* Abase = wpk + (size_t)s * 6144;
        bf16x8 Ah[3], Al[3];
        #pragma unroll
        for (int mt = 0; mt < 3; ++mt) {
            int mg = wm * 3 + mt;
            Ah[mt] = *(const bf16x8*)&Abase[(0 * 6 + mg) * 512 + lane * 8];
            Al[mt] = *(const bf16x8*)&Abase[(1 * 6 + mg) * 512 + lane * 8];
        }
        int kg0 = s * 32 + quad * 8;
        int ci  = kg0 / KP;                // KP pow2 -> shift
        int k0  = kg0 % KP;                // even
        const unsigned int* bh = xbh + ci * rowd + tbase + (k0 >> 1);
        const unsigned int* bl = xbl + ci * rowd + tbase + (k0 >> 1);
        #pragma unroll
        for (int nt = 0; nt < NTW; ++nt) {
            union { unsigned int u[4]; bf16x8 v; } Bh, Bl;
            #pragma unroll
            for (int p = 0; p < 4; p++) {
                Bh.u[p] = bh[nt * 16 + p];
                Bl.u[p] = bl[nt * 16 + p];
            }
            #pragma unroll
            for (int mt = 0; mt < 3; ++mt)
                acc[mt][nt] = __builtin_amdgcn_mfma_f32_16x16x32_bf16(Ah[mt], Bh.v, acc[mt][nt], 0, 0, 0);
            #pragma unroll
            for (int mt = 0; mt < 3; ++mt)
                acc[mt][nt] = __builtin_amdgcn_mfma_f32_16x16x32_bf16(Ah[mt], Bl.v, acc[mt][nt], 0, 0, 0);
            #pragma unroll
            for (int mt = 0; mt < 3; ++mt)
                acc[mt][nt] = __builtin_amdgcn_mfma_f32_16x16x32_bf16(Al[mt], Bh.v, acc[mt][nt], 0, 0, 0);
        }
    }

    // epilogue: C/D layout col=l16 (t), row = quad*4+reg (o within m-tile)
    #pragma unroll
    for (int mt = 0; mt < 3; ++mt) {
        #pragma unroll
        for (int r = 0; r < 4; ++r) {
            int o = wm * 48 + mt * 16 + quad * 4 + r;
            float bv = bias[o];
            #pragma unroll
            for (int nt = 0; nt < NTW; ++nt) {
                int t = tbase + nt * 16;
                if (t < Tout) {
                    float v = acc[mt][nt][r] + bv;
                    if (RELU) v = fmaxf(v, 0.f);
                    size_t oidx = ((size_t)b * CO + o) * Tout + t;
                    if (OUT_BF16) {
                        unsigned int hb = f2b(v);
                        unsigned int lb = f2b(v - b2f(hb));
                        yh[oidx] = (unsigned short)hb;
                        yl[oidx] = (unsigned short)lb;
                    } else {
                        yf[oidx] = v;
                    }
                }
            }
        }
    }
}

// pack w[o][ci][k] -> A image: [step][half][mt6][lane][j8] bf16
template<int KP, int KW, int CI>
__global__ void repack_mfma(const float* __restrict__ w, unsigned short* __restrict__ wpk,
                            int total)
{
    int idx = blockIdx.x * 256 + threadIdx.x;
    if (idx >= total) return;
    int j = idx & 7, lane = (idx >> 3) & 63, g = idx >> 9;
    int c = g / 24, r = g % 24;
    int mt = r % 6, sh = r / 6;            // sh = s*2+half
    int half = sh & 1, s = sh >> 1;
    int S  = c * 2 + s;
    int kg = S * 32 + (lane >> 4) * 8 + j;
    int o  = mt * 16 + (lane & 15);
    int ci = kg / KP, k = kg % KP;
    float val = (k < KW) ? w[((size_t)o * CI + ci) * KW + k] : 0.f;
    unsigned int hb = f2b(val);
    unsigned short out_v;
    if (half == 0) out_v = (unsigned short)hb;
    else           out_v = (unsigned short)f2b(val - b2f(hb));
    wpk[idx] = out_v;
}

// fp32 -> (hi, lo) bf16 split, vectorized x4
__global__ void split_fp32(const float* __restrict__ x, unsigned short* __restrict__ h,
                           unsigned short* __restrict__ l, int n4)
{
    int i = blockIdx.x * 256 + threadIdx.x;
    if (i >= n4) return;
    float4 v = ((const float4*)x)[i];
    unsigned int h0 = f2b(v.x), h1 = f2b(v.y), h2 = f2b(v.z), h3 = f2b(v.w);
    ushort4 hv = make_ushort4((unsigned short)h0, (unsigned short)h1,
                              (unsigned short)h2, (unsigned short)h3);
    ushort4 lv = make_ushort4((unsigned short)f2b(v.x - b2f(h0)),
                              (unsigned short)f2b(v.y - b2f(h1)),
                              (unsigned short)f2b(v.z - b2f(h2)),
                              (unsigned short)f2b(v.w - b2f(h3)));
    ((ushort4*)h)[i] = hv;
    ((ushort4*)l)[i] = lv;
}

// ---------------------------------------------------------------------------
// fp32 tail path (verified): conv5-7, pools, max, head
// ---------------------------------------------------------------------------
template<int K, int CI, int CO, bool RELU>
__global__ __launch_bounds__(256)
void conv_tile2(const float* __restrict__ x, const float* __restrict__ wr,
                const float* __restrict__ bias, float* __restrict__ y,
                int Tin, int Tout)
{
    constexpr int TT    = 64;
    constexpr int SPAN  = 2 * TT - 2 + K;
    constexpr int SPANP = (SPAN + 2) & ~1;
    constexpr int NO    = CO / 4;

    __shared__ float xs[CI * SPANP];

    const int tid  = threadIdx.x;
    const int lane = tid & 63;
    const int wave = __builtin_amdgcn_readfirstlane(tid >> 6);

    const int nT = (Tout + TT - 1) / TT;
    const int b  = blockIdx.x / nT;
    const int t0 = (blockIdx.x % nT) * TT;
    const float* xb = x + (size_t)b * CI * Tin;

    for (int idx = tid; idx < CI * SPANP; idx += 256) {
        int i = idx / SPANP, s = idx - i * SPANP;
        int g = 2 * t0 + s;
        xs[idx] = (s < SPAN && g < Tin) ? xb[(size_t)i * Tin + g] : 0.f;
    }
    __syncthreads();

    float acc[NO];
    #pragma unroll
    for (int oo = 0; oo < NO; oo++) acc[oo] = 0.f;

    const float* wq = wr + wave * NO;
    const int xoff = 2 * lane;

    for (int ci = 0; ci < CI; ci++) {
        float xr[K + (K & 1)];
        #pragma unroll
        for (int p = 0; p < (K + 1) / 2; p++) {
            float2 v = *(const float2*)&xs[ci * SPANP + xoff + 2 * p];
            xr[2 * p]     = v.x;
            xr[2 * p + 1] = v.y;
        }
        #pragma unroll
        for (int k = 0; k < K; k++) {
            const float* wp = wq + (ci * K + k) * CO;
            float xv = xr[k];
            #pragma unroll
            for (int oo = 0; oo < NO; oo++)
                acc[oo] = fmaf(wp[oo], xv, acc[oo]);
        }
    }

    const int o0 = wave * NO;
    const int t  = t0 + lane;
    if (t < Tout) {
        #pragma unroll
        for (int oo = 0; oo < NO; oo++) {
            float v = acc[oo] + bias[o0 + oo];
            if (RELU) v = fmaxf(v, 0.f);
            y[((size_t)b * CO + o0 + oo) * Tout + t] = v;
        }
    }
}

__global__ void repack_w(const float* __restrict__ w, float* __restrict__ wr,
                         int CI, int K, int CO, int total)
{
    int idx = blockIdx.x * 256 + threadIdx.x;
    if (idx >= total) return;
    int o = idx % CO; int rem = idx / CO; int k = rem % K; int ci = rem / K;
    wr[idx] = w[((size_t)o * CI + ci) * K + k];
}

__global__ void pool2_relu(const float* __restrict__ x, float* __restrict__ y,
                           int Tin, int Tout, int total)
{
    int idx = blockIdx.x * 256 + threadIdx.x;
    if (idx >= total) return;
    int t  = idx % Tout;
    int bc = idx / Tout;
    float a = x[(size_t)bc * Tin + 2 * t];
    float b = x[(size_t)bc * Tin + 2 * t + 1];
    y[idx] = fmaxf(0.5f * (a + b), 0.f);
}

__global__ void masked_max(const float* __restrict__ y7, const int* __restrict__ lens,
                           float* __restrict__ feat)
{
    int idx = blockIdx.x * 256 + threadIdx.x;
    if (idx >= 64 * 128) return;
    int b = idx >> 7;
    int L = lens[b];
    L = (L - 10) / 2 + 1;
    L = (L - 5) / 2 + 1;
    L = (L - 5) / 2 + 1;
    L = (L - 5) / 2 + 1;
    L = L / 2;
    L = (L - 5) / 2 + 1;
    L = L / 2;
    L = (L - 5) / 2 + 1;
    L = (L - 3) / 2 + 1;
    const float* p = y7 + (size_t)idx * 14;
    float m = -INFINITY;
    for (int t = 0; t < L; t++) m = fmaxf(m, p[t]);
    feat[idx] = m;
}

__global__ __launch_bounds__(128)
void head_mlp(const float* __restrict__ feat,
              const float* __restrict__ lw1, const float* __restrict__ lb1,
              const float* __restrict__ lw2, const float* __restrict__ lb2,
              const float* __restrict__ lw3, const float* __restrict__ lb3,
              float* __restrict__ out)
{
    __shared__ float f[128], h1[128], h2[64];
    int b = blockIdx.x, tid = threadIdx.x;
    f[tid] = feat[b * 128 + tid];
    __syncthreads();
    {
        float s = lb1[tid];
        for (int i = 0; i < 128; i++) s = fmaf(lw1[tid * 128 + i], f[i], s);
        h1[tid] = fmaxf(s, 0.f);
    }
    __syncthreads();
    if (tid < 64) {
        float s = lb2[tid];
        for (int i = 0; i < 128; i++) s = fmaf(lw2[tid * 128 + i], h1[i], s);
        h2[tid] = fmaxf(s, 0.f);
    }
    __syncthreads();
    if (tid < 5) {
        float s = lb3[tid];
        for (int i = 0; i < 64; i++) s = fmaf(lw3[tid * 64 + i], h2[i], s);
        out[b * 5 + tid] = s;
    }
}

extern "C" void kernel_launch(void* const* d_in, const int* in_sizes, int n_in,
                              void* d_out, int out_size, void* d_ws, size_t ws_size,
                              hipStream_t stream)
{
    const float* x    = (const float*)d_in[0];
    const int*   lens = (const int*)  d_in[1];
    const float* w1 = (const float*)d_in[2];   const float* b1 = (const float*)d_in[3];
    const float* w2 = (const float*)d_in[4];   const float* b2 = (const float*)d_in[5];
    const float* w3 = (const float*)d_in[6];   const float* b3 = (const float*)d_in[7];
    const float* w4 = (const float*)d_in[8];   const float* b4 = (const float*)d_in[9];
    const float* w5 = (const float*)d_in[10];  const float* b5 = (const float*)d_in[11];
    const float* w6 = (const float*)d_in[12];  const float* b6 = (const float*)d_in[13];
    const float* w7 = (const float*)d_in[14];  const float* b7 = (const float*)d_in[15];
    const float* lw1 = (const float*)d_in[16]; const float* lb1 = (const float*)d_in[17];
    const float* lw2 = (const float*)d_in[18]; const float* lb2 = (const float*)d_in[19];
    const float* lw3 = (const float*)d_in[20]; const float* lb3 = (const float*)d_in[21];
    float* out = (float*)d_out;
    char*  W   = (char*)d_ws;

    // lengths: 8192 -> 4092 -> 2044 -> 1020 -> 508 -> 254 -> 125 -> 62 -> 29 -> 14
    size_t off = 0;
    auto take = [&](size_t bytes) {
        size_t o = off; off = (off + bytes + 255) & ~(size_t)255; return o;
    };
    size_t o_y3h = take((size_t)64 * 96 * 1020 * 2 + 4096);
    size_t o_y3l = take((size_t)64 * 96 * 1020 * 2 + 4096);
    size_t o_y4  = take((size_t)64 * 96 * 508 * 4);
    size_t o_y4p = take((size_t)64 * 96 * 254 * 4);
    size_t o_y5  = take((size_t)64 * 96 * 125 * 4);
    size_t o_y5p = take((size_t)64 * 96 * 62 * 4);
    size_t o_y6  = take((size_t)64 * 96 * 29 * 4);
    size_t o_y7  = take((size_t)64 * 128 * 14 * 4);
    size_t o_ft  = take((size_t)64 * 128 * 4);
    size_t o_wp1 = take((size_t)640 * 192 * 2);      // conv1 A image (245 KB)
    size_t o_wp2 = take((size_t)768 * 192 * 2);
    size_t o_wp3 = take((size_t)768 * 192 * 2);
    size_t o_wp4 = take((size_t)768 * 192 * 2);
    size_t o_w5r = take((size_t)96 * 5 * 96 * 4);
    size_t o_w6r = take((size_t)96 * 5 * 96 * 4);
    size_t o_w7r = take((size_t)96 * 3 * 128 * 4);
    size_t persist = off;

    auto chunk_bytes = [&](int Bc) -> size_t {
        size_t s = 0;
        s += 2 * (((size_t)Bc * 40 * 8192 + 2048) * 2 + 256);
        s += 2 * (((size_t)Bc * 96 * 4092 + 2048) * 2 + 256);
        s += 2 * (((size_t)Bc * 96 * 2044 + 2048) * 2 + 256);
        return s;
    };
    int Bc = 64;
    while (Bc > 1 && persist + chunk_bytes(Bc) > ws_size) Bc >>= 1;
    size_t o_xh  = take(((size_t)Bc * 40 * 8192 + 2048) * 2);
    size_t o_xl  = take(((size_t)Bc * 40 * 8192 + 2048) * 2);
    size_t o_y1h = take(((size_t)Bc * 96 * 4092 + 2048) * 2);
    size_t o_y1l = take(((size_t)Bc * 96 * 4092 + 2048) * 2);
    size_t o_y2h = take(((size_t)Bc * 96 * 2044 + 2048) * 2);
    size_t o_y2l = take(((size_t)Bc * 96 * 2044 + 2048) * 2);

    auto US = [&](size_t o) { return (unsigned short*)(W + o); };
    auto FP = [&](size_t o) { return (float*)(W + o); };

    {
        int t1 = 640 * 192;
        repack_mfma<16, 10, 40><<<dim3((t1 + 255) / 256), 256, 0, stream>>>(w1, US(o_wp1), t1);
        int t2 = 768 * 192;
        repack_mfma< 8,  5, 96><<<dim3((t2 + 255) / 256), 256, 0, stream>>>(w2, US(o_wp2), t2);
        repack_mfma< 8,  5, 96><<<dim3((t2 + 255) / 256), 256, 0, stream>>>(w3, US(o_wp3), t2);
        repack_mfma< 8,  5, 96><<<dim3((t2 + 255) / 256), 256, 0, stream>>>(w4, US(o_wp4), t2);
        int t5 = 96 * 5 * 96;
        repack_w<<<dim3((t5 + 255) / 256), 256, 0, stream>>>(w5, FP(o_w5r), 96, 5, 96, t5);
        repack_w<<<dim3((t5 + 255) / 256), 256, 0, stream>>>(w6, FP(o_w6r), 96, 5, 96, t5);
        int t7 = 96 * 3 * 128;
        repack_w<<<dim3((t7 + 255) / 256), 256, 0, stream>>>(w7, FP(o_w7r), 96, 3, 128, t7);
    }

    const int nchunks = 64 / Bc;
    for (int c = 0; c < nchunks; c++) {
        const float* xc = x + (size_t)c * Bc * 40 * 8192;
        int n4 = Bc * 40 * 8192 / 4;
        split_fp32<<<dim3((n4 + 255) / 256), 256, 0, stream>>>(xc, US(o_xh), US(o_xl), n4);

        // grids: B x ceil(Tout/(NTW*16)) x 2 row-halves, 1 wave per block
        conv_mfma_g<16, 10, 40, 8, true, true><<<dim3(Bc * 32 * 2), 64, 0, stream>>>(
            US(o_xh), US(o_xl), US(o_wp1), b1, US(o_y1h), US(o_y1l), nullptr, 8192, 4092);
        conv_mfma_g< 8,  5, 96, 8, true, true><<<dim3(Bc * 16 * 2), 64, 0, stream>>>(
            US(o_y1h), US(o_y1l), US(o_wp2), b2, US(o_y2h), US(o_y2l), nullptr, 4092, 2044);
        unsigned short* y3h_c = US(o_y3h) + (size_t)c * Bc * 96 * 1020;
        unsigned short* y3l_c = US(o_y3l) + (size_t)c * Bc * 96 * 1020;
        conv_mfma_g< 8,  5, 96, 8, true, true><<<dim3(Bc * 8 * 2), 64, 0, stream>>>(
            US(o_y2h), US(o_y2l), US(o_wp3), b3, y3h_c, y3l_c, nullptr, 2044, 1020);
    }

    conv_mfma_g<8, 5, 96, 4, false, false><<<dim3(64 * 8 * 2), 64, 0, stream>>>(
        US(o_y3h), US(o_y3l), US(o_wp4), b4, nullptr, nullptr, FP(o_y4), 1020, 508);

    pool2_relu<<<dim3((64 * 96 * 254 + 255) / 256), 256, 0, stream>>>(FP(o_y4), FP(o_y4p), 508, 254, 64 * 96 * 254);
    conv_tile2<5, 96, 96, false><<<dim3(64 * 2), 256, 0, stream>>>(FP(o_y4p), FP(o_w5r), b5, FP(o_y5), 254, 125);
    pool2_relu<<<dim3((64 * 96 * 62 + 255) / 256), 256, 0, stream>>>(FP(o_y5), FP(o_y5p), 125, 62, 64 * 96 * 62);
    conv_tile2<5, 96, 96, true ><<<dim3(64), 256, 0, stream>>>(FP(o_y5p), FP(o_w6r), b6, FP(o_y6), 62, 29);
    conv_tile2<3, 96, 128, true><<<dim3(64), 256, 0, stream>>>(FP(o_y6), FP(o_w7r), b7, FP(o_y7), 29, 14);
    masked_max<<<dim3(32), 256, 0, stream>>>(FP(o_y7), lens, FP(o_ft));
    head_mlp<<<dim3(64), 128, 0, stream>>>(FP(o_ft), lw1, lb1, lw2, lb2, lw3, lb3, out);
}

// Round 6
// 772.135 us; speedup vs baseline: 1.1112x; 1.1112x over previous
//
#include <hip/hip_runtime.h>
#include <hip/hip_bf16.h>
#include <math.h>

// =============================================================================
// v6: conv1-4 = split-bf16 3-pass MFMA implicit-GEMM, B staged in LDS.
//   Staging is deliberately dumb-simple (direct index math, load->store,
//   no register pipelining, no fused split) after v5's correctness failure.
//   Double-buffered LDS, ONE barrier per K-step:
//     iter s: compute reads Bs[s&1]; stage(s+1) writes Bs[~s&1]; barrier.
//   A (weight fragment image) direct from global dwordx4 (L1-hot, same 12KB
//   for all 4 waves of a block).
// conv5-7 + pools + masked max + MLP head stay on the verified fp32 path.
// =============================================================================

typedef __attribute__((ext_vector_type(8))) short bf16x8;   // 8 bf16 in 4 VGPRs
typedef __attribute__((ext_vector_type(4))) float f32x4;

__device__ __forceinline__ unsigned int f2b(float f) {      // fp32 -> bf16 bits (RNE)
    unsigned int u = __float_as_uint(f);
    return (u + 0x7fffu + ((u >> 16) & 1u)) >> 16;
}
__device__ __forceinline__ float b2f(unsigned int h) { return __uint_as_float(h << 16); }

// ---------------------------------------------------------------------------
// A image (per K-step of 32): [step][half][mg(6)][lane(64)][j(8)] bf16.
// B LDS image (per step): rows r = cil*2+half (cil = channel-in-step), each
// row RD dwords; LDS dword d of a row = global dword t0+d of that channel,
// i.e. elements (2*(t0+d), 2*(t0+d)+1).
// Lane (quad q, l16), n-tile nt reads dwords base+nt*16+p, p=0..3 where
// base = row(cil*2+half)*RD + wc0 + l16 + dwo;  cil=(q*8)/KP, dwo=((q*8)%KP)/2.
// ---------------------------------------------------------------------------
template<int KP, int CI, int NBLK, bool RELU, bool OUT_BF16>
__global__ __launch_bounds__(256)
void conv_mfma6(const unsigned short* __restrict__ xh,
                const unsigned short* __restrict__ xl,
                const unsigned short* __restrict__ wpk,
                const float* __restrict__ bias,
                unsigned short* __restrict__ yh,
                unsigned short* __restrict__ yl,
                float* __restrict__ yf,
                int Tin, int Tout)
{
    constexpr int CO    = 96;
    constexpr int STEPS = CI * KP / 32;
    constexpr int NCI   = 32 / KP;              // channels per K-step
    constexpr int RD    = NBLK + KP / 2 + 2;    // dwords per staged row
    constexpr int ROWS  = NCI * 2;              // x hi/lo halves
    constexpr int NTW   = NBLK / 64;            // n-tiles per wave
    constexpr int TOT   = ROWS * RD;
    constexpr int NIT   = (TOT + 255) / 256;

    __shared__ unsigned int Bs[2][TOT];

    const int tid  = threadIdx.x;
    const int lane = tid & 63;
    const int wave = tid >> 6;
    const int quad = lane >> 4;
    const int l16  = lane & 15;
    const int wc0  = wave * (NBLK / 4);

    const int nT = (Tout + NBLK - 1) / NBLK;
    const int b  = blockIdx.x / nT;
    const int t0 = (blockIdx.x % nT) * NBLK;

    const unsigned int* xbh = (const unsigned int*)xh + (((size_t)b * CI * Tin) >> 1);
    const unsigned int* xbl = (const unsigned int*)xl + (((size_t)b * CI * Tin) >> 1);
    const int rowd = Tin >> 1;                  // dwords per channel row

    // stage step s's channel windows into Bs[buf] (dumb-simple, verifiable)
    auto stage = [&](int s, int buf) {
        const int ci0 = s * NCI;
        #pragma unroll
        for (int it = 0; it < NIT; ++it) {
            int i = tid + it * 256;
            if (i < TOT) {
                int r = i / RD, d = i - r * RD;        // RD constexpr
                int cil = r >> 1, half = r & 1;
                const unsigned int* src =
                    (half ? xbl : xbh) + (size_t)(ci0 + cil) * rowd + t0 + d;
                Bs[buf][i] = *src;   // overruns land in padded-tap cols / slack
            }
        }
    };

    f32x4 acc[6][NTW];
    #pragma unroll
    for (int mt = 0; mt < 6; ++mt)
        #pragma unroll
        for (int nt = 0; nt < NTW; ++nt) acc[mt][nt] = (f32x4)0.f;

    const int cil = (quad * 8) / KP;            // channel row for this quad
    const int dwo = ((quad * 8) % KP) >> 1;     // dword offset from k0

    stage(0, 0);
    __syncthreads();

    for (int s = 0; s < STEPS; ++s) {
        const int buf = s & 1;

        // A fragments (per-lane 16B, identical across waves -> L1-hot)
        const unsigned short* Ab = wpk + (size_t)s * 6144;
        bf16x8 Ah[6], Al[6];
        #pragma unroll
        for (int mt = 0; mt < 6; ++mt) {
            Ah[mt] = *(const bf16x8*)&Ab[(mt) * 512 + lane * 8];
            Al[mt] = *(const bf16x8*)&Ab[(6 + mt) * 512 + lane * 8];
        }
        const unsigned int* bh = &Bs[buf][(cil * 2 + 0) * RD + wc0 + l16 + dwo];
        const unsigned int* bl = &Bs[buf][(cil * 2 + 1) * RD + wc0 + l16 + dwo];
        #pragma unroll
        for (int nt = 0; nt < NTW; ++nt) {
            union { unsigned int u[4]; bf16x8 v; } Bh, Bl;
            #pragma unroll
            for (int p = 0; p < 4; ++p) {
                Bh.u[p] = bh[nt * 16 + p];
                Bl.u[p] = bl[nt * 16 + p];
            }
            #pragma unroll
            for (int mt = 0; mt < 6; ++mt)
                acc[mt][nt] = __builtin_amdgcn_mfma_f32_16x16x32_bf16(Ah[mt], Bh.v, acc[mt][nt], 0, 0, 0);
            #pragma unroll
            for (int mt = 0; mt < 6; ++mt)
                acc[mt][nt] = __builtin_amdgcn_mfma_f32_16x16x32_bf16(Ah[mt], Bl.v, acc[mt][nt], 0, 0, 0);
            #pragma unroll
            for (int mt = 0; mt < 6; ++mt)
                acc[mt][nt] = __builtin_amdgcn_mfma_f32_16x16x32_bf16(Al[mt], Bh.v, acc[mt][nt], 0, 0, 0);
        }

        if (s + 1 < STEPS) stage(s + 1, buf ^ 1);   // writes only Bs[buf^1]
        __syncthreads();
    }

    // epilogue: C/D layout col=l16 (t), row = quad*4+reg
    #pragma unroll
    for (int mt = 0; mt < 6; ++mt) {
        #pragma unroll
        for (int r = 0; r < 4; ++r) {
            int o = mt * 16 + quad * 4 + r;
            float bv = bias[o];
            #pragma unroll
            for (int nt = 0; nt < NTW; ++nt) {
                int t = t0 + wc0 + nt * 16 + l16;
                if (t < Tout) {
                    float v = acc[mt][nt][r] + bv;
                    if (RELU) v = fmaxf(v, 0.f);
                    size_t oidx = ((size_t)b * CO + o) * Tout + t;
                    if (OUT_BF16) {
                        unsigned int hb = f2b(v);
                        unsigned int lb = f2b(v - b2f(hb));
                        yh[oidx] = (unsigned short)hb;
                        yl[oidx] = (unsigned short)lb;
                    } else {
                        yf[oidx] = v;
                    }
                }
            }
        }
    }
}

// pack w[o][ci][k] -> A image: [step][half][mt6][lane][j8] bf16
template<int KP, int KW, int CI>
__global__ void repack_mfma(const float* __restrict__ w, unsigned short* __restrict__ wpk,
                            int total)
{
    int idx = blockIdx.x * 256 + threadIdx.x;
    if (idx >= total) return;
    int j = idx & 7, lane = (idx >> 3) & 63, g = idx >> 9;
    int c = g / 24, r = g % 24;
    int mt = r % 6, sh = r / 6;            // sh = s*2+half
    int half = sh & 1, s = sh >> 1;
    int S  = c * 2 + s;
    int kg = S * 32 + (lane >> 4) * 8 + j;
    int o  = mt * 16 + (lane & 15);
    int ci = kg / KP, k = kg % KP;
    float val = (k < KW) ? w[((size_t)o * CI + ci) * KW + k] : 0.f;
    unsigned int hb = f2b(val);
    unsigned short out_v;
    if (half == 0) out_v = (unsigned short)hb;
    else           out_v = (unsigned short)f2b(val - b2f(hb));
    wpk[idx] = out_v;
}

// fp32 -> (hi, lo) bf16 split, vectorized x4 (verified v4 path)
__global__ void split_fp32(const float* __restrict__ x, unsigned short* __restrict__ h,
                           unsigned short* __restrict__ l, int n4)
{
    int i = blockIdx.x * 256 + threadIdx.x;
    if (i >= n4) return;
    float4 v = ((const float4*)x)[i];
    unsigned int h0 = f2b(v.x), h1 = f2b(v.y), h2 = f2b(v.z), h3 = f2b(v.w);
    ushort4 hv = make_ushort4((unsigned short)h0, (unsigned short)h1,
                              (unsigned short)h2, (unsigned short)h3);
    ushort4 lv = make_ushort4((unsigned short)f2b(v.x - b2f(h0)),
                              (unsigned short)f2b(v.y - b2f(h1)),
                              (unsigned short)f2b(v.z - b2f(h2)),
                              (unsigned short)f2b(v.w - b2f(h3)));
    ((ushort4*)h)[i] = hv;
    ((ushort4*)l)[i] = lv;
}

// ---------------------------------------------------------------------------
// fp32 tail path (verified): conv5-7, pools, max, head
// ---------------------------------------------------------------------------
template<int K, int CI, int CO, bool RELU>
__global__ __launch_bounds__(256)
void conv_tile2(const float* __restrict__ x, const float* __restrict__ wr,
                const float* __restrict__ bias, float* __restrict__ y,
                int Tin, int Tout)
{
    constexpr int TT    = 64;
    constexpr int SPAN  = 2 * TT - 2 + K;
    constexpr int SPANP = (SPAN + 2) & ~1;
    constexpr int NO    = CO / 4;

    __shared__ float xs[CI * SPANP];

    const int tid  = threadIdx.x;
    const int lane = tid & 63;
    const int wave = __builtin_amdgcn_readfirstlane(tid >> 6);

    const int nT = (Tout + TT - 1) / TT;
    const int b  = blockIdx.x / nT;
    const int t0 = (blockIdx.x % nT) * TT;
    const float* xb = x + (size_t)b * CI * Tin;

    for (int idx = tid; idx < CI * SPANP; idx += 256) {
        int i = idx / SPANP, s = idx - i * SPANP;
        int g = 2 * t0 + s;
        xs[idx] = (s < SPAN && g < Tin) ? xb[(size_t)i * Tin + g] : 0.f;
    }
    __syncthreads();

    float acc[NO];
    #pragma unroll
    for (int oo = 0; oo < NO; oo++) acc[oo] = 0.f;

    const float* wq = wr + wave * NO;
    const int xoff = 2 * lane;

    for (int ci = 0; ci < CI; ci++) {
        float xr[K + (K & 1)];
        #pragma unroll
        for (int p = 0; p < (K + 1) / 2; p++) {
            float2 v = *(const float2*)&xs[ci * SPANP + xoff + 2 * p];
            xr[2 * p]     = v.x;
            xr[2 * p + 1] = v.y;
        }
        #pragma unroll
        for (int k = 0; k < K; k++) {
            const float* wp = wq + (ci * K + k) * CO;
            float xv = xr[k];
            #pragma unroll
            for (int oo = 0; oo < NO; oo++)
                acc[oo] = fmaf(wp[oo], xv, acc[oo]);
        }
    }

    const int o0 = wave * NO;
    const int t  = t0 + lane;
    if (t < Tout) {
        #pragma unroll
        for (int oo = 0; oo < NO; oo++) {
            float v = acc[oo] + bias[o0 + oo];
            if (RELU) v = fmaxf(v, 0.f);
            y[((size_t)b * CO + o0 + oo) * Tout + t] = v;
        }
    }
}

__global__ void repack_w(const float* __restrict__ w, float* __restrict__ wr,
                         int CI, int K, int CO, int total)
{
    int idx = blockIdx.x * 256 + threadIdx.x;
    if (idx >= total) return;
    int o = idx % CO; int rem = idx / CO; int k = rem % K; int ci = rem / K;
    wr[idx] = w[((size_t)o * CI + ci) * K + k];
}

__global__ void pool2_relu(const float* __restrict__ x, float* __restrict__ y,
                           int Tin, int Tout, int total)
{
    int idx = blockIdx.x * 256 + threadIdx.x;
    if (idx >= total) return;
    int t  = idx % Tout;
    int bc = idx / Tout;
    float a = x[(size_t)bc * Tin + 2 * t];
    float b = x[(size_t)bc * Tin + 2 * t + 1];
    y[idx] = fmaxf(0.5f * (a + b), 0.f);
}

__global__ void masked_max(const float* __restrict__ y7, const int* __restrict__ lens,
                           float* __restrict__ feat)
{
    int idx = blockIdx.x * 256 + threadIdx.x;
    if (idx >= 64 * 128) return;
    int b = idx >> 7;
    int L = lens[b];
    L = (L - 10) / 2 + 1;
    L = (L - 5) / 2 + 1;
    L = (L - 5) / 2 + 1;
    L = (L - 5) / 2 + 1;
    L = L / 2;
    L = (L - 5) / 2 + 1;
    L = L / 2;
    L = (L - 5) / 2 + 1;
    L = (L - 3) / 2 + 1;
    const float* p = y7 + (size_t)idx * 14;
    float m = -INFINITY;
    for (int t = 0; t < L; t++) m = fmaxf(m, p[t]);
    feat[idx] = m;
}

__global__ __launch_bounds__(128)
void head_mlp(const float* __restrict__ feat,
              const float* __restrict__ lw1, const float* __restrict__ lb1,
              const float* __restrict__ lw2, const float* __restrict__ lb2,
              const float* __restrict__ lw3, const float* __restrict__ lb3,
              float* __restrict__ out)
{
    __shared__ float f[128], h1[128], h2[64];
    int b = blockIdx.x, tid = threadIdx.x;
    f[tid] = feat[b * 128 + tid];
    __syncthreads();
    {
        float s = lb1[tid];
        for (int i = 0; i < 128; i++) s = fmaf(lw1[tid * 128 + i], f[i], s);
        h1[tid] = fmaxf(s, 0.f);
    }
    __syncthreads();
    if (tid < 64) {
        float s = lb2[tid];
        for (int i = 0; i < 128; i++) s = fmaf(lw2[tid * 128 + i], h1[i], s);
        h2[tid] = fmaxf(s, 0.f);
    }
    __syncthreads();
    if (tid < 5) {
        float s = lb3[tid];
        for (int i = 0; i < 64; i++) s = fmaf(lw3[tid * 64 + i], h2[i], s);
        out[b * 5 + tid] = s;
    }
}

extern "C" void kernel_launch(void* const* d_in, const int* in_sizes, int n_in,
                              void* d_out, int out_size, void* d_ws, size_t ws_size,
                              hipStream_t stream)
{
    const float* x    = (const float*)d_in[0];
    const int*   lens = (const int*)  d_in[1];
    const float* w1 = (const float*)d_in[2];   const float* b1 = (const float*)d_in[3];
    const float* w2 = (const float*)d_in[4];   const float* b2 = (const float*)d_in[5];
    const float* w3 = (const float*)d_in[6];   const float* b3 = (const float*)d_in[7];
    const float* w4 = (const float*)d_in[8];   const float* b4 = (const float*)d_in[9];
    const float* w5 = (const float*)d_in[10];  const float* b5 = (const float*)d_in[11];
    const float* w6 = (const float*)d_in[12];  const float* b6 = (const float*)d_in[13];
    const float* w7 = (const float*)d_in[14];  const float* b7 = (const float*)d_in[15];
    const float* lw1 = (const float*)d_in[16]; const float* lb1 = (const float*)d_in[17];
    const float* lw2 = (const float*)d_in[18]; const float* lb2 = (const float*)d_in[19];
    const float* lw3 = (const float*)d_in[20]; const float* lb3 = (const float*)d_in[21];
    float* out = (float*)d_out;
    char*  W   = (char*)d_ws;

    // lengths: 8192 -> 4092 -> 2044 -> 1020 -> 508 -> 254 -> 125 -> 62 -> 29 -> 14
    size_t off = 0;
    auto take = [&](size_t bytes) {
        size_t o = off; off = (off + bytes + 255) & ~(size_t)255; return o;
    };
    size_t o_y3h = take((size_t)64 * 96 * 1020 * 2 + 4096);
    size_t o_y3l = take((size_t)64 * 96 * 1020 * 2 + 4096);
    size_t o_y4  = take((size_t)64 * 96 * 508 * 4);
    size_t o_y4p = take((size_t)64 * 96 * 254 * 4);
    size_t o_y5  = take((size_t)64 * 96 * 125 * 4);
    size_t o_y5p = take((size_t)64 * 96 * 62 * 4);
    size_t o_y6  = take((size_t)64 * 96 * 29 * 4);
    size_t o_y7  = take((size_t)64 * 128 * 14 * 4);
    size_t o_ft  = take((size_t)64 * 128 * 4);
    size_t o_wp1 = take((size_t)640 * 192 * 2);
    size_t o_wp2 = take((size_t)768 * 192 * 2);
    size_t o_wp3 = take((size_t)768 * 192 * 2);
    size_t o_wp4 = take((size_t)768 * 192 * 2);
    size_t o_w5r = take((size_t)96 * 5 * 96 * 4);
    size_t o_w6r = take((size_t)96 * 5 * 96 * 4);
    size_t o_w7r = take((size_t)96 * 3 * 128 * 4);
    size_t persist = off;

    auto chunk_bytes = [&](int Bc) -> size_t {
        size_t s = 0;
        s += 2 * (((size_t)Bc * 40 * 8192 + 2048) * 2 + 256);
        s += 2 * (((size_t)Bc * 96 * 4092 + 2048) * 2 + 256);
        s += 2 * (((size_t)Bc * 96 * 2044 + 2048) * 2 + 256);
        return s;
    };
    int Bc = 64;
    while (Bc > 1 && persist + chunk_bytes(Bc) > ws_size) Bc >>= 1;
    size_t o_xh  = take(((size_t)Bc * 40 * 8192 + 2048) * 2);
    size_t o_xl  = take(((size_t)Bc * 40 * 8192 + 2048) * 2);
    size_t o_y1h = take(((size_t)Bc * 96 * 4092 + 2048) * 2);
    size_t o_y1l = take(((size_t)Bc * 96 * 4092 + 2048) * 2);
    size_t o_y2h = take(((size_t)Bc * 96 * 2044 + 2048) * 2);
    size_t o_y2l = take(((size_t)Bc * 96 * 2044 + 2048) * 2);

    auto US = [&](size_t o) { return (unsigned short*)(W + o); };
    auto FP = [&](size_t o) { return (float*)(W + o); };

    {
        int t1 = 640 * 192;
        repack_mfma<16, 10, 40><<<dim3((t1 + 255) / 256), 256, 0, stream>>>(w1, US(o_wp1), t1);
        int t2 = 768 * 192;
        repack_mfma< 8,  5, 96><<<dim3((t2 + 255) / 256), 256, 0, stream>>>(w2, US(o_wp2), t2);
        repack_mfma< 8,  5, 96><<<dim3((t2 + 255) / 256), 256, 0, stream>>>(w3, US(o_wp3), t2);
        repack_mfma< 8,  5, 96><<<dim3((t2 + 255) / 256), 256, 0, stream>>>(w4, US(o_wp4), t2);
        int t5 = 96 * 5 * 96;
        repack_w<<<dim3((t5 + 255) / 256), 256, 0, stream>>>(w5, FP(o_w5r), 96, 5, 96, t5);
        repack_w<<<dim3((t5 + 255) / 256), 256, 0, stream>>>(w6, FP(o_w6r), 96, 5, 96, t5);
        int t7 = 96 * 3 * 128;
        repack_w<<<dim3((t7 + 255) / 256), 256, 0, stream>>>(w7, FP(o_w7r), 96, 3, 128, t7);
    }

    const int nchunks = 64 / Bc;
    for (int c = 0; c < nchunks; c++) {
        const float* xc = x + (size_t)c * Bc * 40 * 8192;
        int n4 = Bc * 40 * 8192 / 4;
        split_fp32<<<dim3((n4 + 255) / 256), 256, 0, stream>>>(xc, US(o_xh), US(o_xl), n4);

        // conv1: KP=16, NBLK=256 -> nT=16
        conv_mfma6<16, 40, 256, true, true><<<dim3(Bc * 16), 256, 0, stream>>>(
            US(o_xh), US(o_xl), US(o_wp1), b1, US(o_y1h), US(o_y1l), nullptr, 8192, 4092);
        // conv2: KP=8, NBLK=256 -> nT=8
        conv_mfma6< 8, 96, 256, true, true><<<dim3(Bc * 8), 256, 0, stream>>>(
            US(o_y1h), US(o_y1l), US(o_wp2), b2, US(o_y2h), US(o_y2l), nullptr, 4092, 2044);
        // conv3: KP=8, NBLK=128 -> nT=8
        unsigned short* y3h_c = US(o_y3h) + (size_t)c * Bc * 96 * 1020;
        unsigned short* y3l_c = US(o_y3l) + (size_t)c * Bc * 96 * 1020;
        conv_mfma6< 8, 96, 128, true, true><<<dim3(Bc * 8), 256, 0, stream>>>(
            US(o_y2h), US(o_y2l), US(o_wp3), b3, y3h_c, y3l_c, nullptr, 2044, 1020);
    }

    // conv4: KP=8, NBLK=128 -> nT=4, fp32 out
    conv_mfma6<8, 96, 128, false, false><<<dim3(64 * 4), 256, 0, stream>>>(
        US(o_y3h), US(o_y3l), US(o_wp4), b4, nullptr, nullptr, FP(o_y4), 1020, 508);

    pool2_relu<<<dim3((64 * 96 * 254 + 255) / 256), 256, 0, stream>>>(FP(o_y4), FP(o_y4p), 508, 254, 64 * 96 * 254);
    conv_tile2<5, 96, 96, false><<<dim3(64 * 2), 256, 0, stream>>>(FP(o_y4p), FP(o_w5r), b5, FP(o_y5), 254, 125);
    pool2_relu<<<dim3((64 * 96 * 62 + 255) / 256), 256, 0, stream>>>(FP(o_y5), FP(o_y5p), 125, 62, 64 * 96 * 62);
    conv_tile2<5, 96, 96, true ><<<dim3(64), 256, 0, stream>>>(FP(o_y5p), FP(o_w6r), b6, FP(o_y6), 62, 29);
    conv_tile2<3, 96, 128, true><<<dim3(64), 256, 0, stream>>>(FP(o_y6), FP(o_w7r), b7, FP(o_y7), 29, 14);
    masked_max<<<dim3(32), 256, 0, stream>>>(FP(o_y7), lens, FP(o_ft));
    head_mlp<<<dim3(64), 128, 0, stream>>>(FP(o_ft), lw1, lb1, lw2, lb2, lw3, lb3, out);
}

// Round 7
// 669.600 us; speedup vs baseline: 1.2813x; 1.1531x over previous
//
#include <hip/hip_runtime.h>
#include <hip/hip_bf16.h>
#include <math.h>

// =============================================================================
// v7: conv1-4 = split-bf16 3-pass MFMA implicit-GEMM; BOTH operands in LDS.
//   A (weight fragment image): global_load_lds 16B DMA (v3-verified pattern),
//     double-buffered 2x12KB; shared by all 4 waves -> no per-wave global A.
//   B (activations): v6-verified dumb-simple staging, but split into
//     load->regs (issued BEFORE the MFMAs, latency hidden) and regs->LDS
//     (after MFMAs, before barrier). No cross-barrier register carry.
//   One barrier per K-step; stage(s+1) writes buf^1 while compute reads buf.
// conv5-7 + pools + masked max + MLP head stay on the verified fp32 path.
// =============================================================================

typedef __attribute__((ext_vector_type(8))) short bf16x8;   // 8 bf16 in 4 VGPRs
typedef __attribute__((ext_vector_type(4))) float f32x4;

__device__ __forceinline__ unsigned int f2b(float f) {      // fp32 -> bf16 bits (RNE)
    unsigned int u = __float_as_uint(f);
    return (u + 0x7fffu + ((u >> 16) & 1u)) >> 16;
}
__device__ __forceinline__ float b2f(unsigned int h) { return __uint_as_float(h << 16); }

__device__ __forceinline__ void stage16(const void* g, void* l) {
    __builtin_amdgcn_global_load_lds(
        (const __attribute__((address_space(1))) unsigned int*)g,
        (__attribute__((address_space(3))) unsigned int*)l, 16, 0, 0);
}

// ---------------------------------------------------------------------------
// A image (per K-step of 32): [step][half][mg(6)][lane(64)][j(8)] bf16 = 12KB.
// B LDS image (per step): rows r = cil*2+half, RD dwords each; dword d of a
// row = global dword t0+d of that channel (elements 2*(t0+d), 2*(t0+d)+1).
// Lane (quad q, l16), n-tile nt reads dwords base+nt*16+p, p=0..3,
// base = (cil*2+half)*RD + wc0 + l16 + dwo; cil=(q*8)/KP, dwo=((q*8)%KP)/2.
// ---------------------------------------------------------------------------
template<int KP, int CI, int NBLK, bool RELU, bool OUT_BF16>
__global__ __launch_bounds__(256)
void conv_mfma7(const unsigned short* __restrict__ xh,
                const unsigned short* __restrict__ xl,
                const unsigned short* __restrict__ wpk,
                const float* __restrict__ bias,
                unsigned short* __restrict__ yh,
                unsigned short* __restrict__ yl,
                float* __restrict__ yf,
                int Tin, int Tout)
{
    constexpr int CO    = 96;
    constexpr int STEPS = CI * KP / 32;
    constexpr int NCI   = 32 / KP;              // channels per K-step
    constexpr int RD    = NBLK + KP / 2 + 2;    // dwords per staged row
    constexpr int ROWS  = NCI * 2;              // x hi/lo halves
    constexpr int NTW   = NBLK / 64;            // n-tiles per wave
    constexpr int TOT   = ROWS * RD;
    constexpr int NIT   = (TOT + 255) / 256;

    __shared__ __align__(16) unsigned short As[2][6144];   // 24 KB A dbuf
    __shared__ unsigned int Bs[2][TOT];                    // B dbuf

    const int tid  = threadIdx.x;
    const int lane = tid & 63;
    const int wave = tid >> 6;
    const int quad = lane >> 4;
    const int l16  = lane & 15;
    const int wc0  = wave * (NBLK / 4);

    const int nT = (Tout + NBLK - 1) / NBLK;
    const int b  = blockIdx.x / nT;
    const int t0 = (blockIdx.x % nT) * NBLK;

    const unsigned int* xbh = (const unsigned int*)xh + (((size_t)b * CI * Tin) >> 1);
    const unsigned int* xbl = (const unsigned int*)xl + (((size_t)b * CI * Tin) >> 1);
    const int rowd = Tin >> 1;                  // dwords per channel row

    // ---- A staging: 12 segments of 1KB, DMA 16B per lane (v3 pattern) ----
    auto stageA = [&](int s, int buf) {
        const char* g = (const char*)(wpk + (size_t)s * 6144) + (size_t)lane * 16;
        char* l = (char*)&As[buf][0] + (size_t)lane * 16;
        #pragma unroll
        for (int i = 0; i < 3; ++i) {
            int seg = i * 4 + wave;
            stage16(g + seg * 1024, l + seg * 1024);
        }
    };

    // ---- B staging: v6-verified index math, split load / store ----
    unsigned int breg[NIT];
    auto loadB = [&](int s) {
        const int ci0 = s * NCI;
        #pragma unroll
        for (int it = 0; it < NIT; ++it) {
            int i = tid + it * 256;
            if (i < TOT) {
                int r = i / RD, d = i - r * RD;        // RD constexpr
                int cil = r >> 1, half = r & 1;
                breg[it] = *((half ? xbl : xbh) + (size_t)(ci0 + cil) * rowd + t0 + d);
            }
        }
    };
    auto storeB = [&](int buf) {
        #pragma unroll
        for (int it = 0; it < NIT; ++it) {
            int i = tid + it * 256;
            if (i < TOT) Bs[buf][i] = breg[it];
        }
    };

    f32x4 acc[6][NTW];
    #pragma unroll
    for (int mt = 0; mt < 6; ++mt)
        #pragma unroll
        for (int nt = 0; nt < NTW; ++nt) acc[mt][nt] = (f32x4)0.f;

    const int cil = (quad * 8) / KP;            // channel row for this quad
    const int dwo = ((quad * 8) % KP) >> 1;     // dword offset from k0

    loadB(0); storeB(0); stageA(0, 0);
    __syncthreads();

    for (int s = 0; s < STEPS; ++s) {
        const int buf = s & 1;

        if (s + 1 < STEPS) {
            loadB(s + 1);               // global loads in flight during MFMAs
            stageA(s + 1, buf ^ 1);     // DMA into the other A buffer
        }

        // A fragments from LDS (ds_read_b128, 16B-aligned)
        bf16x8 Ah[6], Al[6];
        #pragma unroll
        for (int mt = 0; mt < 6; ++mt) {
            Ah[mt] = *(const bf16x8*)&As[buf][(mt) * 512 + lane * 8];
            Al[mt] = *(const bf16x8*)&As[buf][(6 + mt) * 512 + lane * 8];
        }
        const unsigned int* bh = &Bs[buf][(cil * 2 + 0) * RD + wc0 + l16 + dwo];
        const unsigned int* bl = &Bs[buf][(cil * 2 + 1) * RD + wc0 + l16 + dwo];
        #pragma unroll
        for (int nt = 0; nt < NTW; ++nt) {
            union { unsigned int u[4]; bf16x8 v; } Bh, Bl;
            #pragma unroll
            for (int p = 0; p < 4; ++p) {
                Bh.u[p] = bh[nt * 16 + p];
                Bl.u[p] = bl[nt * 16 + p];
            }
            #pragma unroll
            for (int mt = 0; mt < 6; ++mt)
                acc[mt][nt] = __builtin_amdgcn_mfma_f32_16x16x32_bf16(Ah[mt], Bh.v, acc[mt][nt], 0, 0, 0);
            #pragma unroll
            for (int mt = 0; mt < 6; ++mt)
                acc[mt][nt] = __builtin_amdgcn_mfma_f32_16x16x32_bf16(Ah[mt], Bl.v, acc[mt][nt], 0, 0, 0);
            #pragma unroll
            for (int mt = 0; mt < 6; ++mt)
                acc[mt][nt] = __builtin_amdgcn_mfma_f32_16x16x32_bf16(Al[mt], Bh.v, acc[mt][nt], 0, 0, 0);
        }

        if (s + 1 < STEPS) storeB(buf ^ 1);   // writes only Bs[buf^1]
        __syncthreads();                      // drains DMA + B loads + waves
    }

    // epilogue: C/D layout col=l16 (t), row = quad*4+reg
    #pragma unroll
    for (int mt = 0; mt < 6; ++mt) {
        #pragma unroll
        for (int r = 0; r < 4; ++r) {
            int o = mt * 16 + quad * 4 + r;
            float bv = bias[o];
            #pragma unroll
            for (int nt = 0; nt < NTW; ++nt) {
                int t = t0 + wc0 + nt * 16 + l16;
                if (t < Tout) {
                    float v = acc[mt][nt][r] + bv;
                    if (RELU) v = fmaxf(v, 0.f);
                    size_t oidx = ((size_t)b * CO + o) * Tout + t;
                    if (OUT_BF16) {
                        unsigned int hb = f2b(v);
                        unsigned int lb = f2b(v - b2f(hb));
                        yh[oidx] = (unsigned short)hb;
                        yl[oidx] = (unsigned short)lb;
                    } else {
                        yf[oidx] = v;
                    }
                }
            }
        }
    }
}

// pack w[o][ci][k] -> A image: [step][half][mt6][lane][j8] bf16
template<int KP, int KW, int CI>
__global__ void repack_mfma(const float* __restrict__ w, unsigned short* __restrict__ wpk,
                            int total)
{
    int idx = blockIdx.x * 256 + threadIdx.x;
    if (idx >= total) return;
    int j = idx & 7, lane = (idx >> 3) & 63, g = idx >> 9;
    int c = g / 24, r = g % 24;
    int mt = r % 6, sh = r / 6;            // sh = s*2+half
    int half = sh & 1, s = sh >> 1;
    int S  = c * 2 + s;
    int kg = S * 32 + (lane >> 4) * 8 + j;
    int o  = mt * 16 + (lane & 15);
    int ci = kg / KP, k = kg % KP;
    float val = (k < KW) ? w[((size_t)o * CI + ci) * KW + k] : 0.f;
    unsigned int hb = f2b(val);
    unsigned short out_v;
    if (half == 0) out_v = (unsigned short)hb;
    else           out_v = (unsigned short)f2b(val - b2f(hb));
    wpk[idx] = out_v;
}

// fp32 -> (hi, lo) bf16 split, vectorized x4 (verified)
__global__ void split_fp32(const float* __restrict__ x, unsigned short* __restrict__ h,
                           unsigned short* __restrict__ l, int n4)
{
    int i = blockIdx.x * 256 + threadIdx.x;
    if (i >= n4) return;
    float4 v = ((const float4*)x)[i];
    unsigned int h0 = f2b(v.x), h1 = f2b(v.y), h2 = f2b(v.z), h3 = f2b(v.w);
    ushort4 hv = make_ushort4((unsigned short)h0, (unsigned short)h1,
                              (unsigned short)h2, (unsigned short)h3);
    ushort4 lv = make_ushort4((unsigned short)f2b(v.x - b2f(h0)),
                              (unsigned short)f2b(v.y - b2f(h1)),
                              (unsigned short)f2b(v.z - b2f(h2)),
                              (unsigned short)f2b(v.w - b2f(h3)));
    ((ushort4*)h)[i] = hv;
    ((ushort4*)l)[i] = lv;
}

// ---------------------------------------------------------------------------
// fp32 tail path (verified): conv5-7, pools, max, head
// ---------------------------------------------------------------------------
template<int K, int CI, int CO, bool RELU>
__global__ __launch_bounds__(256)
void conv_tile2(const float* __restrict__ x, const float* __restrict__ wr,
                const float* __restrict__ bias, float* __restrict__ y,
                int Tin, int Tout)
{
    constexpr int TT    = 64;
    constexpr int SPAN  = 2 * TT - 2 + K;
    constexpr int SPANP = (SPAN + 2) & ~1;
    constexpr int NO    = CO / 4;

    __shared__ float xs[CI * SPANP];

    const int tid  = threadIdx.x;
    const int lane = tid & 63;
    const int wave = __builtin_amdgcn_readfirstlane(tid >> 6);

    const int nT = (Tout + TT - 1) / TT;
    const int b  = blockIdx.x / nT;
    const int t0 = (blockIdx.x % nT) * TT;
    const float* xb = x + (size_t)b * CI * Tin;

    for (int idx = tid; idx < CI * SPANP; idx += 256) {
        int i = idx / SPANP, s = idx - i * SPANP;
        int g = 2 * t0 + s;
        xs[idx] = (s < SPAN && g < Tin) ? xb[(size_t)i * Tin + g] : 0.f;
    }
    __syncthreads();

    float acc[NO];
    #pragma unroll
    for (int oo = 0; oo < NO; oo++) acc[oo] = 0.f;

    const float* wq = wr + wave * NO;
    const int xoff = 2 * lane;

    for (int ci = 0; ci < CI; ci++) {
        float xr[K + (K & 1)];
        #pragma unroll
        for (int p = 0; p < (K + 1) / 2; p++) {
            float2 v = *(const float2*)&xs[ci * SPANP + xoff + 2 * p];
            xr[2 * p]     = v.x;
            xr[2 * p + 1] = v.y;
        }
        #pragma unroll
        for (int k = 0; k < K; k++) {
            const float* wp = wq + (ci * K + k) * CO;
            float xv = xr[k];
            #pragma unroll
            for (int oo = 0; oo < NO; oo++)
                acc[oo] = fmaf(wp[oo], xv, acc[oo]);
        }
    }

    const int o0 = wave * NO;
    const int t  = t0 + lane;
    if (t < Tout) {
        #pragma unroll
        for (int oo = 0; oo < NO; oo++) {
            float v = acc[oo] + bias[o0 + oo];
            if (RELU) v = fmaxf(v, 0.f);
            y[((size_t)b * CO + o0 + oo) * Tout + t] = v;
        }
    }
}

__global__ void repack_w(const float* __restrict__ w, float* __restrict__ wr,
                         int CI, int K, int CO, int total)
{
    int idx = blockIdx.x * 256 + threadIdx.x;
    if (idx >= total) return;
    int o = idx % CO; int rem = idx / CO; int k = rem % K; int ci = rem / K;
    wr[idx] = w[((size_t)o * CI + ci) * K + k];
}

__global__ void pool2_relu(const float* __restrict__ x, float* __restrict__ y,
                           int Tin, int Tout, int total)
{
    int idx = blockIdx.x * 256 + threadIdx.x;
    if (idx >= total) return;
    int t  = idx % Tout;
    int bc = idx / Tout;
    float a = x[(size_t)bc * Tin + 2 * t];
    float b = x[(size_t)bc * Tin + 2 * t + 1];
    y[idx] = fmaxf(0.5f * (a + b), 0.f);
}

__global__ void masked_max(const float* __restrict__ y7, const int* __restrict__ lens,
                           float* __restrict__ feat)
{
    int idx = blockIdx.x * 256 + threadIdx.x;
    if (idx >= 64 * 128) return;
    int b = idx >> 7;
    int L = lens[b];
    L = (L - 10) / 2 + 1;
    L = (L - 5) / 2 + 1;
    L = (L - 5) / 2 + 1;
    L = (L - 5) / 2 + 1;
    L = L / 2;
    L = (L - 5) / 2 + 1;
    L = L / 2;
    L = (L - 5) / 2 + 1;
    L = (L - 3) / 2 + 1;
    const float* p = y7 + (size_t)idx * 14;
    float m = -INFINITY;
    for (int t = 0; t < L; t++) m = fmaxf(m, p[t]);
    feat[idx] = m;
}

__global__ __launch_bounds__(128)
void head_mlp(const float* __restrict__ feat,
              const float* __restrict__ lw1, const float* __restrict__ lb1,
              const float* __restrict__ lw2, const float* __restrict__ lb2,
              const float* __restrict__ lw3, const float* __restrict__ lb3,
              float* __restrict__ out)
{
    __shared__ float f[128], h1[128], h2[64];
    int b = blockIdx.x, tid = threadIdx.x;
    f[tid] = feat[b * 128 + tid];
    __syncthreads();
    {
        float s = lb1[tid];
        for (int i = 0; i < 128; i++) s = fmaf(lw1[tid * 128 + i], f[i], s);
        h1[tid] = fmaxf(s, 0.f);
    }
    __syncthreads();
    if (tid < 64) {
        float s = lb2[tid];
        for (int i = 0; i < 128; i++) s = fmaf(lw2[tid * 128 + i], h1[i], s);
        h2[tid] = fmaxf(s, 0.f);
    }
    __syncthreads();
    if (tid < 5) {
        float s = lb3[tid];
        for (int i = 0; i < 64; i++) s = fmaf(lw3[tid * 64 + i], h2[i], s);
        out[b * 5 + tid] = s;
    }
}

extern "C" void kernel_launch(void* const* d_in, const int* in_sizes, int n_in,
                              void* d_out, int out_size, void* d_ws, size_t ws_size,
                              hipStream_t stream)
{
    const float* x    = (const float*)d_in[0];
    const int*   lens = (const int*)  d_in[1];
    const float* w1 = (const float*)d_in[2];   const float* b1 = (const float*)d_in[3];
    const float* w2 = (const float*)d_in[4];   const float* b2 = (const float*)d_in[5];
    const float* w3 = (const float*)d_in[6];   const float* b3 = (const float*)d_in[7];
    const float* w4 = (const float*)d_in[8];   const float* b4 = (const float*)d_in[9];
    const float* w5 = (const float*)d_in[10];  const float* b5 = (const float*)d_in[11];
    const float* w6 = (const float*)d_in[12];  const float* b6 = (const float*)d_in[13];
    const float* w7 = (const float*)d_in[14];  const float* b7 = (const float*)d_in[15];
    const float* lw1 = (const float*)d_in[16]; const float* lb1 = (const float*)d_in[17];
    const float* lw2 = (const float*)d_in[18]; const float* lb2 = (const float*)d_in[19];
    const float* lw3 = (const float*)d_in[20]; const float* lb3 = (const float*)d_in[21];
    float* out = (float*)d_out;
    char*  W   = (char*)d_ws;

    // lengths: 8192 -> 4092 -> 2044 -> 1020 -> 508 -> 254 -> 125 -> 62 -> 29 -> 14
    size_t off = 0;
    auto take = [&](size_t bytes) {
        size_t o = off; off = (off + bytes + 255) & ~(size_t)255; return o;
    };
    size_t o_y3h = take((size_t)64 * 96 * 1020 * 2 + 4096);
    size_t o_y3l = take((size_t)64 * 96 * 1020 * 2 + 4096);
    size_t o_y4  = take((size_t)64 * 96 * 508 * 4);
    size_t o_y4p = take((size_t)64 * 96 * 254 * 4);
    size_t o_y5  = take((size_t)64 * 96 * 125 * 4);
    size_t o_y5p = take((size_t)64 * 96 * 62 * 4);
    size_t o_y6  = take((size_t)64 * 96 * 29 * 4);
    size_t o_y7  = take((size_t)64 * 128 * 14 * 4);
    size_t o_ft  = take((size_t)64 * 128 * 4);
    size_t o_wp1 = take((size_t)640 * 192 * 2);
    size_t o_wp2 = take((size_t)768 * 192 * 2);
    size_t o_wp3 = take((size_t)768 * 192 * 2);
    size_t o_wp4 = take((size_t)768 * 192 * 2);
    size_t o_w5r = take((size_t)96 * 5 * 96 * 4);
    size_t o_w6r = take((size_t)96 * 5 * 96 * 4);
    size_t o_w7r = take((size_t)96 * 3 * 128 * 4);
    size_t persist = off;

    auto chunk_bytes = [&](int Bc) -> size_t {
        size_t s = 0;
        s += 2 * (((size_t)Bc * 40 * 8192 + 2048) * 2 + 256);
        s += 2 * (((size_t)Bc * 96 * 4092 + 2048) * 2 + 256);
        s += 2 * (((size_t)Bc * 96 * 2044 + 2048) * 2 + 256);
        return s;
    };
    int Bc = 64;
    while (Bc > 1 && persist + chunk_bytes(Bc) > ws_size) Bc >>= 1;
    size_t o_xh  = take(((size_t)Bc * 40 * 8192 + 2048) * 2);
    size_t o_xl  = take(((size_t)Bc * 40 * 8192 + 2048) * 2);
    size_t o_y1h = take(((size_t)Bc * 96 * 4092 + 2048) * 2);
    size_t o_y1l = take(((size_t)Bc * 96 * 4092 + 2048) * 2);
    size_t o_y2h = take(((size_t)Bc * 96 * 2044 + 2048) * 2);
    size_t o_y2l = take(((size_t)Bc * 96 * 2044 + 2048) * 2);

    auto US = [&](size_t o) { return (unsigned short*)(W + o); };
    auto FP = [&](size_t o) { return (float*)(W + o); };

    {
        int t1 = 640 * 192;
        repack_mfma<16, 10, 40><<<dim3((t1 + 255) / 256), 256, 0, stream>>>(w1, US(o_wp1), t1);
        int t2 = 768 * 192;
        repack_mfma< 8,  5, 96><<<dim3((t2 + 255) / 256), 256, 0, stream>>>(w2, US(o_wp2), t2);
        repack_mfma< 8,  5, 96><<<dim3((t2 + 255) / 256), 256, 0, stream>>>(w3, US(o_wp3), t2);
        repack_mfma< 8,  5, 96><<<dim3((t2 + 255) / 256), 256, 0, stream>>>(w4, US(o_wp4), t2);
        int t5 = 96 * 5 * 96;
        repack_w<<<dim3((t5 + 255) / 256), 256, 0, stream>>>(w5, FP(o_w5r), 96, 5, 96, t5);
        repack_w<<<dim3((t5 + 255) / 256), 256, 0, stream>>>(w6, FP(o_w6r), 96, 5, 96, t5);
        int t7 = 96 * 3 * 128;
        repack_w<<<dim3((t7 + 255) / 256), 256, 0, stream>>>(w7, FP(o_w7r), 96, 3, 128, t7);
    }

    const int nchunks = 64 / Bc;
    for (int c = 0; c < nchunks; c++) {
        const float* xc = x + (size_t)c * Bc * 40 * 8192;
        int n4 = Bc * 40 * 8192 / 4;
        split_fp32<<<dim3((n4 + 255) / 256), 256, 0, stream>>>(xc, US(o_xh), US(o_xl), n4);

        // conv1: KP=16, NBLK=256 -> nT=16
        conv_mfma7<16, 40, 256, true, true><<<dim3(Bc * 16), 256, 0, stream>>>(
            US(o_xh), US(o_xl), US(o_wp1), b1, US(o_y1h), US(o_y1l), nullptr, 8192, 4092);
        // conv2: KP=8, NBLK=256 -> nT=8
        conv_mfma7< 8, 96, 256, true, true><<<dim3(Bc * 8), 256, 0, stream>>>(
            US(o_y1h), US(o_y1l), US(o_wp2), b2, US(o_y2h), US(o_y2l), nullptr, 4092, 2044);
        // conv3: KP=8, NBLK=128 -> nT=8
        unsigned short* y3h_c = US(o_y3h) + (size_t)c * Bc * 96 * 1020;
        unsigned short* y3l_c = US(o_y3l) + (size_t)c * Bc * 96 * 1020;
        conv_mfma7< 8, 96, 128, true, true><<<dim3(Bc * 8), 256, 0, stream>>>(
            US(o_y2h), US(o_y2l), US(o_wp3), b3, y3h_c, y3l_c, nullptr, 2044, 1020);
    }

    // conv4: KP=8, NBLK=128 -> nT=4, fp32 out
    conv_mfma7<8, 96, 128, false, false><<<dim3(64 * 4), 256, 0, stream>>>(
        US(o_y3h), US(o_y3l), US(o_wp4), b4, nullptr, nullptr, FP(o_y4), 1020, 508);

    pool2_relu<<<dim3((64 * 96 * 254 + 255) / 256), 256, 0, stream>>>(FP(o_y4), FP(o_y4p), 508, 254, 64 * 96 * 254);
    conv_tile2<5, 96, 96, false><<<dim3(64 * 2), 256, 0, stream>>>(FP(o_y4p), FP(o_w5r), b5, FP(o_y5), 254, 125);
    pool2_relu<<<dim3((64 * 96 * 62 + 255) / 256), 256, 0, stream>>>(FP(o_y5), FP(o_y5p), 125, 62, 64 * 96 * 62);
    conv_tile2<5, 96, 96, true ><<<dim3(64), 256, 0, stream>>>(FP(o_y5p), FP(o_w6r), b6, FP(o_y6), 62, 29);
    conv_tile2<3, 96, 128, true><<<dim3(64), 256, 0, stream>>>(FP(o_y6), FP(o_w7r), b7, FP(o_y7), 29, 14);
    masked_max<<<dim3(32), 256, 0, stream>>>(FP(o_y7), lens, FP(o_ft));
    head_mlp<<<dim3(64), 128, 0, stream>>>(FP(o_ft), lw1, lb1, lw2, lb2, lw3, lb3, out);
}

// Round 8
// 500.840 us; speedup vs baseline: 1.7131x; 1.3370x over previous
//
#include <hip/hip_runtime.h>
#include <hip/hip_bf16.h>
#include <math.h>

// =============================================================================
// v8: conv1-4 = split-fp16 2-PASS MFMA implicit-GEMM (v7 loop skeleton):
//   A = weights split hi+lo fp16 (exact to ~2^-21), staged by global_load_lds
//       DMA, double-buffered.  B = activations as SINGLE fp16 plane (per-layer
//       rel err ~2^-11), staged via v6-verified index math.  2 MFMA passes
//       (Ah*B + Al*B) instead of 3 -> 2/3 matrix work, 1/2 staging traffic.
//   Launch count 19 -> 8: one repack kernel; pool1 fused into conv4 epilogue,
//   pool2 into conv5 epilogue (shfl_xor pair-average); conv6+conv7+masked
//   max+MLP head fused into one per-sample LDS-resident kernel.
// =============================================================================

typedef __attribute__((ext_vector_type(8))) _Float16 f16x8;  // 8 fp16 in 4 VGPRs
typedef __attribute__((ext_vector_type(4))) float f32x4;

__device__ __forceinline__ unsigned short f2h_bits(float f) {
    union { _Float16 h; unsigned short u; } cv;
    cv.h = (_Float16)f;                      // v_cvt_f16_f32, RNE
    return cv.u;
}

__device__ __forceinline__ void stage16(const void* g, void* l) {
    __builtin_amdgcn_global_load_lds(
        (const __attribute__((address_space(1))) unsigned int*)g,
        (__attribute__((address_space(3))) unsigned int*)l, 16, 0, 0);
}

// ---------------------------------------------------------------------------
// A image (per K-step of 32): [step][half(hi/lo)][mg(6)][lane(64)][j(8)] fp16.
// B LDS image (per step): NCI rows of RD dwords; dword d of row = elements
// (2*(t0+d), 2*(t0+d)+1) of that channel.  Lane (quad q,l16) frag = 4 dwords
// at cil*RD + wc0 + l16 + dwo + nt*16;  cil=(q*8)/KP, dwo=((q*8)%KP)/2.
// ---------------------------------------------------------------------------
template<int KP, int CI, int NBLK, bool RELU, bool OUT_F16, bool POOL>
__global__ __launch_bounds__(256)
void conv_mfma8(const unsigned short* __restrict__ xh,
                const unsigned short* __restrict__ wpk,
                const float* __restrict__ bias,
                unsigned short* __restrict__ yh,
                float* __restrict__ yf,
                int Tin, int Tout)
{
    constexpr int CO    = 96;
    constexpr int STEPS = CI * KP / 32;
    constexpr int NCI   = 32 / KP;              // channels per K-step
    constexpr int RD    = NBLK + KP / 2 + 2;    // dwords per staged row
    constexpr int NTW   = NBLK / 64;            // n-tiles per wave
    constexpr int TOT   = NCI * RD;
    constexpr int NIT   = (TOT + 255) / 256;

    __shared__ __align__(16) unsigned short As[2][6144];   // 24 KB A dbuf
    __shared__ unsigned int Bs[2][TOT];                    // B dbuf (fp16 pairs)

    const int tid  = threadIdx.x;
    const int lane = tid & 63;
    const int wave = tid >> 6;
    const int quad = lane >> 4;
    const int l16  = lane & 15;
    const int wc0  = wave * (NBLK / 4);

    const int nT = (Tout + NBLK - 1) / NBLK;
    const int b  = blockIdx.x / nT;
    const int t0 = (blockIdx.x % nT) * NBLK;

    const unsigned int* xb = (const unsigned int*)xh + (((size_t)b * CI * Tin) >> 1);
    const int rowd = Tin >> 1;                  // dwords per channel row

    auto stageA = [&](int s, int buf) {
        const char* g = (const char*)(wpk + (size_t)s * 6144) + (size_t)lane * 16;
        char* l = (char*)&As[buf][0] + (size_t)lane * 16;
        #pragma unroll
        for (int i = 0; i < 3; ++i) {
            int seg = i * 4 + wave;
            stage16(g + seg * 1024, l + seg * 1024);
        }
    };

    unsigned int breg[NIT];
    auto loadB = [&](int s) {
        const int ci0 = s * NCI;
        #pragma unroll
        for (int it = 0; it < NIT; ++it) {
            int i = tid + it * 256;
            if (i < TOT) {
                int r = i / RD, d = i - r * RD;        // RD constexpr
                breg[it] = *(xb + (size_t)(ci0 + r) * rowd + t0 + d);
            }
        }
    };
    auto storeB = [&](int buf) {
        #pragma unroll
        for (int it = 0; it < NIT; ++it) {
            int i = tid + it * 256;
            if (i < TOT) Bs[buf][i] = breg[it];
        }
    };

    f32x4 acc[6][NTW];
    #pragma unroll
    for (int mt = 0; mt < 6; ++mt)
        #pragma unroll
        for (int nt = 0; nt < NTW; ++nt) acc[mt][nt] = (f32x4)0.f;

    const int cil = (quad * 8) / KP;
    const int dwo = ((quad * 8) % KP) >> 1;

    loadB(0); storeB(0); stageA(0, 0);
    __syncthreads();

    for (int s = 0; s < STEPS; ++s) {
        const int buf = s & 1;

        if (s + 1 < STEPS) {
            loadB(s + 1);               // global loads in flight during MFMAs
            stageA(s + 1, buf ^ 1);
        }

        f16x8 Ah[6], Al[6];
        #pragma unroll
        for (int mt = 0; mt < 6; ++mt) {
            Ah[mt] = *(const f16x8*)&As[buf][(mt) * 512 + lane * 8];
            Al[mt] = *(const f16x8*)&As[buf][(6 + mt) * 512 + lane * 8];
        }
        const unsigned int* bp = &Bs[buf][cil * RD + wc0 + l16 + dwo];
        #pragma unroll
        for (int nt = 0; nt < NTW; ++nt) {
            union { unsigned int u[4]; f16x8 v; } Bv;
            #pragma unroll
            for (int p = 0; p < 4; ++p) Bv.u[p] = bp[nt * 16 + p];
            #pragma unroll
            for (int mt = 0; mt < 6; ++mt)
                acc[mt][nt] = __builtin_amdgcn_mfma_f32_16x16x32_f16(Ah[mt], Bv.v, acc[mt][nt], 0, 0, 0);
            #pragma unroll
            for (int mt = 0; mt < 6; ++mt)
                acc[mt][nt] = __builtin_amdgcn_mfma_f32_16x16x32_f16(Al[mt], Bv.v, acc[mt][nt], 0, 0, 0);
        }

        if (s + 1 < STEPS) storeB(buf ^ 1);
        __syncthreads();
    }

    // epilogue: C/D layout col=l16 (t), row = quad*4+reg
    #pragma unroll
    for (int mt = 0; mt < 6; ++mt) {
        #pragma unroll
        for (int r = 0; r < 4; ++r) {
            int o = mt * 16 + quad * 4 + r;
            float bv = bias[o];
            #pragma unroll
            for (int nt = 0; nt < NTW; ++nt) {
                int t = t0 + wc0 + nt * 16 + l16;
                float v = acc[mt][nt][r] + bv;
                if (RELU) v = fmaxf(v, 0.f);
                if (POOL) {
                    // AvgPool(2) + ReLU fused: pairs live in adjacent lanes
                    float sum = v + __shfl_xor(v, 1, 64);
                    if ((lane & 1) == 0 && t + 1 < Tout)
                        yf[((size_t)b * CO + o) * (Tout >> 1) + (t >> 1)] =
                            fmaxf(0.5f * sum, 0.f);
                } else if (t < Tout) {
                    size_t oidx = ((size_t)b * CO + o) * Tout + t;
                    if (OUT_F16) yh[oidx] = f2h_bits(v);
                    else         yf[oidx] = v;
                }
            }
        }
    }
}

// ---------------------------------------------------------------------------
// single repack kernel: 4 MFMA A-images (fp16 hi/lo) + 3 fp32 [ci][k][o]
// ---------------------------------------------------------------------------
__device__ __forceinline__ void repack_img(const float* __restrict__ w,
                                           unsigned short* __restrict__ wpk,
                                           int idx, int KP, int KW, int CI)
{
    int j = idx & 7, lane = (idx >> 3) & 63, g = idx >> 9;
    int c = g / 24, r = g % 24;
    int mt = r % 6, sh = r / 6;
    int half = sh & 1, s = sh >> 1;
    int S  = c * 2 + s;
    int kg = S * 32 + (lane >> 4) * 8 + j;
    int o  = mt * 16 + (lane & 15);
    int ci = kg / KP, k = kg % KP;
    float val = (k < KW) ? w[((size_t)o * CI + ci) * KW + k] : 0.f;
    _Float16 hh = (_Float16)val;
    union { _Float16 h; unsigned short u; } cv;
    cv.h = (half == 0) ? hh : (_Float16)(val - (float)hh);
    wpk[idx] = cv.u;
}
__device__ __forceinline__ void repack_okc(const float* __restrict__ w,
                                           float* __restrict__ wr,
                                           int idx, int CI, int K, int CO)
{
    int o = idx % CO; int rem = idx / CO; int k = rem % K; int ci = rem / K;
    wr[idx] = w[((size_t)o * CI + ci) * K + k];
}

__global__ void repack_all(const float* w1, const float* w2, const float* w3,
                           const float* w4, const float* w5, const float* w6,
                           const float* w7,
                           unsigned short* p1, unsigned short* p2,
                           unsigned short* p3, unsigned short* p4,
                           float* r5, float* r6, float* r7)
{
    int idx = blockIdx.x * 256 + threadIdx.x;
    if (idx < 122880) { repack_img(w1, p1, idx, 16, 10, 40); return; }
    idx -= 122880;
    if (idx < 147456) { repack_img(w2, p2, idx, 8, 5, 96); return; }
    idx -= 147456;
    if (idx < 147456) { repack_img(w3, p3, idx, 8, 5, 96); return; }
    idx -= 147456;
    if (idx < 147456) { repack_img(w4, p4, idx, 8, 5, 96); return; }
    idx -= 147456;
    if (idx < 46080)  { repack_okc(w5, r5, idx, 96, 5, 96); return; }
    idx -= 46080;
    if (idx < 46080)  { repack_okc(w6, r6, idx, 96, 5, 96); return; }
    idx -= 46080;
    if (idx < 36864)  { repack_okc(w7, r7, idx, 96, 3, 128); return; }
}

// fp32 -> fp16 conversion, vectorized x4
__global__ void split_fp16(const float* __restrict__ x, unsigned short* __restrict__ h,
                           int n4)
{
    int i = blockIdx.x * 256 + threadIdx.x;
    if (i >= n4) return;
    float4 v = ((const float4*)x)[i];
    ((ushort4*)h)[i] = make_ushort4(f2h_bits(v.x), f2h_bits(v.y),
                                    f2h_bits(v.z), f2h_bits(v.w));
}

// ---------------------------------------------------------------------------
// fp32 conv5 (verified conv_tile2) with optional fused AvgPool2+ReLU epilogue
// ---------------------------------------------------------------------------
template<int K, int CI, int CO, bool RELU, bool POOL>
__global__ __launch_bounds__(256)
void conv_tile2(const float* __restrict__ x, const float* __restrict__ wr,
                const float* __restrict__ bias, float* __restrict__ y,
                int Tin, int Tout)
{
    constexpr int TT    = 64;
    constexpr int SPAN  = 2 * TT - 2 + K;
    constexpr int SPANP = (SPAN + 2) & ~1;
    constexpr int NO    = CO / 4;

    __shared__ float xs[CI * SPANP];

    const int tid  = threadIdx.x;
    const int lane = tid & 63;
    const int wave = __builtin_amdgcn_readfirstlane(tid >> 6);

    const int nT = (Tout + TT - 1) / TT;
    const int b  = blockIdx.x / nT;
    const int t0 = (blockIdx.x % nT) * TT;
    const float* xb = x + (size_t)b * CI * Tin;

    for (int idx = tid; idx < CI * SPANP; idx += 256) {
        int i = idx / SPANP, s = idx - i * SPANP;
        int g = 2 * t0 + s;
        xs[idx] = (s < SPAN && g < Tin) ? xb[(size_t)i * Tin + g] : 0.f;
    }
    __syncthreads();

    float acc[NO];
    #pragma unroll
    for (int oo = 0; oo < NO; oo++) acc[oo] = 0.f;

    const float* wq = wr + wave * NO;
    const int xoff = 2 * lane;

    for (int ci = 0; ci < CI; ci++) {
        float xr[K + (K & 1)];
        #pragma unroll
        for (int p = 0; p < (K + 1) / 2; p++) {
            float2 v = *(const float2*)&xs[ci * SPANP + xoff + 2 * p];
            xr[2 * p]     = v.x;
            xr[2 * p + 1] = v.y;
        }
        #pragma unroll
        for (int k = 0; k < K; k++) {
            const float* wp = wq + (ci * K + k) * CO;
            float xv = xr[k];
            #pragma unroll
            for (int oo = 0; oo < NO; oo++)
                acc[oo] = fmaf(wp[oo], xv, acc[oo]);
        }
    }

    const int o0 = wave * NO;
    const int t  = t0 + lane;
    #pragma unroll
    for (int oo = 0; oo < NO; oo++) {
        float v = acc[oo] + bias[o0 + oo];
        if (RELU) v = fmaxf(v, 0.f);
        if (POOL) {
            float sum = v + __shfl_xor(v, 1, 64);
            if ((lane & 1) == 0 && t + 1 < Tout)
                y[((size_t)b * CO + o0 + oo) * (Tout >> 1) + (t >> 1)] =
                    fmaxf(0.5f * sum, 0.f);
        } else if (t < Tout) {
            y[((size_t)b * CO + o0 + oo) * Tout + t] = v;
        }
    }
}

// ---------------------------------------------------------------------------
// fused tail: per sample, LDS-resident  y5p -> conv6 -> conv7 -> masked max
// -> MLP head -> out.  64 blocks x 256 threads.
// ---------------------------------------------------------------------------
__global__ __launch_bounds__(256)
void tail_fused(const float* __restrict__ y5p,
                const float* __restrict__ w6r, const float* __restrict__ b6,
                const float* __restrict__ w7r, const float* __restrict__ b7,
                const int* __restrict__ lens,
                const float* __restrict__ lw1, const float* __restrict__ lb1,
                const float* __restrict__ lw2, const float* __restrict__ lb2,
                const float* __restrict__ lw3, const float* __restrict__ lb3,
                float* __restrict__ out)
{
    __shared__ float s5[96 * 62];
    __shared__ float s6[96 * 29];
    __shared__ float s7[128 * 14];
    __shared__ float feat[128], h1[128], h2[64];

    const int b = blockIdx.x, tid = threadIdx.x;
    const int lane = tid & 63;
    const int wave = __builtin_amdgcn_readfirstlane(tid >> 6);

    for (int i = tid; i < 96 * 62; i += 256) s5[i] = y5p[(size_t)b * 96 * 62 + i];
    __syncthreads();

    // conv6: 96 -> 96, K=5, stride 2, 62 -> 29, relu
    {
        const int t = lane;
        if (t < 29) {
            float a6[24];
            #pragma unroll
            for (int oo = 0; oo < 24; oo++) a6[oo] = 0.f;
            const float* wq = w6r + wave * 24;
            for (int ci = 0; ci < 96; ci++) {
                float xr[5];
                #pragma unroll
                for (int k = 0; k < 5; k++) xr[k] = s5[ci * 62 + 2 * t + k];
                #pragma unroll
                for (int k = 0; k < 5; k++) {
                    const float* wp = wq + (ci * 5 + k) * 96;
                    #pragma unroll
                    for (int oo = 0; oo < 24; oo++)
                        a6[oo] = fmaf(wp[oo], xr[k], a6[oo]);
                }
            }
            #pragma unroll
            for (int oo = 0; oo < 24; oo++) {
                int o = wave * 24 + oo;
                s6[o * 29 + t] = fmaxf(a6[oo] + b6[o], 0.f);
            }
        }
    }
    __syncthreads();

    // conv7: 96 -> 128, K=3, stride 2, 29 -> 14, relu
    {
        const int t = lane;
        if (t < 14) {
            float a7[32];
            #pragma unroll
            for (int oo = 0; oo < 32; oo++) a7[oo] = 0.f;
            const float* wq = w7r + wave * 32;
            for (int ci = 0; ci < 96; ci++) {
                float xr[3];
                #pragma unroll
                for (int k = 0; k < 3; k++) xr[k] = s6[ci * 29 + 2 * t + k];
                #pragma unroll
                for (int k = 0; k < 3; k++) {
                    const float* wp = wq + (ci * 3 + k) * 128;
                    #pragma unroll
                    for (int oo = 0; oo < 32; oo++)
                        a7[oo] = fmaf(wp[oo], xr[k], a7[oo]);
                }
            }
            #pragma unroll
            for (int oo = 0; oo < 32; oo++) {
                int o = wave * 32 + oo;
                s7[o * 14 + t] = fmaxf(a7[oo] + b7[o], 0.f);
            }
        }
    }
    __syncthreads();

    // masked max over valid prefix
    if (tid < 128) {
        int L = lens[b];
        L = (L - 10) / 2 + 1;
        L = (L - 5) / 2 + 1;
        L = (L - 5) / 2 + 1;
        L = (L - 5) / 2 + 1;
        L = L / 2;
        L = (L - 5) / 2 + 1;
        L = L / 2;
        L = (L - 5) / 2 + 1;
        L = (L - 3) / 2 + 1;
        float m = -INFINITY;
        for (int t = 0; t < L; t++) m = fmaxf(m, s7[tid * 14 + t]);
        feat[tid] = m;
    }
    __syncthreads();

    // MLP head 128 -> relu 128 -> relu 64 -> 5
    if (tid < 128) {
        float s = lb1[tid];
        for (int i = 0; i < 128; i++) s = fmaf(lw1[tid * 128 + i], feat[i], s);
        h1[tid] = fmaxf(s, 0.f);
    }
    __syncthreads();
    if (tid < 64) {
        float s = lb2[tid];
        for (int i = 0; i < 128; i++) s = fmaf(lw2[tid * 128 + i], h1[i], s);
        h2[tid] = fmaxf(s, 0.f);
    }
    __syncthreads();
    if (tid < 5) {
        float s = lb3[tid];
        for (int i = 0; i < 64; i++) s = fmaf(lw3[tid * 64 + i], h2[i], s);
        out[b * 5 + tid] = s;
    }
}

extern "C" void kernel_launch(void* const* d_in, const int* in_sizes, int n_in,
                              void* d_out, int out_size, void* d_ws, size_t ws_size,
                              hipStream_t stream)
{
    const float* x    = (const float*)d_in[0];
    const int*   lens = (const int*)  d_in[1];
    const float* w1 = (const float*)d_in[2];   const float* b1 = (const float*)d_in[3];
    const float* w2 = (const float*)d_in[4];   const float* b2 = (const float*)d_in[5];
    const float* w3 = (const float*)d_in[6];   const float* b3 = (const float*)d_in[7];
    const float* w4 = (const float*)d_in[8];   const float* b4 = (const float*)d_in[9];
    const float* w5 = (const float*)d_in[10];  const float* b5 = (const float*)d_in[11];
    const float* w6 = (const float*)d_in[12];  const float* b6 = (const float*)d_in[13];
    const float* w7 = (const float*)d_in[14];  const float* b7 = (const float*)d_in[15];
    const float* lw1 = (const float*)d_in[16]; const float* lb1 = (const float*)d_in[17];
    const float* lw2 = (const float*)d_in[18]; const float* lb2 = (const float*)d_in[19];
    const float* lw3 = (const float*)d_in[20]; const float* lb3 = (const float*)d_in[21];
    float* out = (float*)d_out;
    char*  W   = (char*)d_ws;

    // lengths: 8192 -> 4092 -> 2044 -> 1020 -> 508 -> 254 -> 125 -> 62 -> 29 -> 14
    size_t off = 0;
    auto take = [&](size_t bytes) {
        size_t o = off; off = (off + bytes + 255) & ~(size_t)255; return o;
    };
    size_t o_y3h = take(((size_t)64 * 96 * 1020 + 2048) * 2);
    size_t o_y4p = take((size_t)64 * 96 * 254 * 4);
    size_t o_y5p = take((size_t)64 * 96 * 62 * 4);
    size_t o_wp1 = take((size_t)122880 * 2);
    size_t o_wp2 = take((size_t)147456 * 2);
    size_t o_wp3 = take((size_t)147456 * 2);
    size_t o_wp4 = take((size_t)147456 * 2);
    size_t o_w5r = take((size_t)46080 * 4);
    size_t o_w6r = take((size_t)46080 * 4);
    size_t o_w7r = take((size_t)36864 * 4);
    size_t persist = off;

    auto chunk_bytes = [&](int Bc) -> size_t {
        size_t s = 0;
        s += ((size_t)Bc * 40 * 8192 + 2048) * 2 + 256;
        s += ((size_t)Bc * 96 * 4092 + 2048) * 2 + 256;
        s += ((size_t)Bc * 96 * 2044 + 2048) * 2 + 256;
        return s;
    };
    int Bc = 64;
    while (Bc > 1 && persist + chunk_bytes(Bc) > ws_size) Bc >>= 1;
    size_t o_xh  = take(((size_t)Bc * 40 * 8192 + 2048) * 2);
    size_t o_y1h = take(((size_t)Bc * 96 * 4092 + 2048) * 2);
    size_t o_y2h = take(((size_t)Bc * 96 * 2044 + 2048) * 2);

    auto US = [&](size_t o) { return (unsigned short*)(W + o); };
    auto FP = [&](size_t o) { return (float*)(W + o); };

    // one repack kernel for everything (694272 elements)
    repack_all<<<dim3((694272 + 255) / 256), 256, 0, stream>>>(
        w1, w2, w3, w4, w5, w6, w7,
        US(o_wp1), US(o_wp2), US(o_wp3), US(o_wp4),
        FP(o_w5r), FP(o_w6r), FP(o_w7r));

    const int nchunks = 64 / Bc;
    for (int c = 0; c < nchunks; c++) {
        const float* xc = x + (size_t)c * Bc * 40 * 8192;
        int n4 = Bc * 40 * 8192 / 4;
        split_fp16<<<dim3((n4 + 255) / 256), 256, 0, stream>>>(xc, US(o_xh), n4);

        // conv1: KP=16, NBLK=256 -> nT=16
        conv_mfma8<16, 40, 256, true, true, false><<<dim3(Bc * 16), 256, 0, stream>>>(
            US(o_xh), US(o_wp1), b1, US(o_y1h), nullptr, 8192, 4092);
        // conv2: KP=8, NBLK=256 -> nT=8
        conv_mfma8< 8, 96, 256, true, true, false><<<dim3(Bc * 8), 256, 0, stream>>>(
            US(o_y1h), US(o_wp2), b2, US(o_y2h), nullptr, 4092, 2044);
        // conv3: KP=8, NBLK=128 -> nT=8
        unsigned short* y3h_c = US(o_y3h) + (size_t)c * Bc * 96 * 1020;
        conv_mfma8< 8, 96, 128, true, true, false><<<dim3(Bc * 8), 256, 0, stream>>>(
            US(o_y2h), US(o_wp3), b3, y3h_c, nullptr, 2044, 1020);
    }

    // conv4: KP=8, NBLK=128 -> nT=4; fused AvgPool2+ReLU -> y4p (fp32, 254)
    conv_mfma8<8, 96, 128, false, false, true><<<dim3(64 * 4), 256, 0, stream>>>(
        US(o_y3h), US(o_wp4), b4, nullptr, FP(o_y4p), 1020, 508);

    // conv5 (fp32) with fused AvgPool2+ReLU -> y5p (fp32, 62)
    conv_tile2<5, 96, 96, false, true><<<dim3(64 * 2), 256, 0, stream>>>(
        FP(o_y4p), FP(o_w5r), b5, FP(o_y5p), 254, 125);

    // conv6 + conv7 + masked max + MLP head, one kernel per sample
    tail_fused<<<dim3(64), 256, 0, stream>>>(
        FP(o_y5p), FP(o_w6r), b6, FP(o_w7r), b7, lens,
        lw1, lb1, lw2, lb2, lw3, lb3, out);
}

// Round 9
// 463.302 us; speedup vs baseline: 1.8519x; 1.0810x over previous
//
#include <hip/hip_runtime.h>
#include <hip/hip_bf16.h>
#include <math.h>

// =============================================================================
// v9: conv1-5 = split-fp16 2-pass MFMA implicit-GEMM (v7/v8-verified skeleton).
//   - conv1 converts fp32->fp16 inside loadB (split_fp16 kernel + 126MB gone).
//   - conv4 pool-epilogue emits fp16 plane -> conv5 is now MFMA too.
//   - Tail un-serialized: conv6 own kernel @256 blocks (s_load weights);
//     conv7+maskedmax+head in one 64-block kernel with ci split across lane
//     sub-quads + shfl_xor butterfly reduction (all 64 lanes busy).
// =============================================================================

typedef __attribute__((ext_vector_type(8))) _Float16 f16x8;  // 8 fp16 in 4 VGPRs
typedef __attribute__((ext_vector_type(4))) float f32x4;

__device__ __forceinline__ unsigned short f2h_bits(float f) {
    union { _Float16 h; unsigned short u; } cv;
    cv.h = (_Float16)f;                      // v_cvt_f16_f32, RNE
    return cv.u;
}

__device__ __forceinline__ void stage16(const void* g, void* l) {
    __builtin_amdgcn_global_load_lds(
        (const __attribute__((address_space(1))) unsigned int*)g,
        (__attribute__((address_space(3))) unsigned int*)l, 16, 0, 0);
}

// ---------------------------------------------------------------------------
// A image (per K-step of 32): [step][half(hi/lo)][mg(6)][lane(64)][j(8)] fp16.
// B LDS image (per step): NCI rows of RD dwords; dword d of row = elements
// (2*(t0+d), 2*(t0+d)+1).  Lane (quad q,l16) frag = 4 dwords at
// cil*RD + wc0 + l16 + dwo + nt*16;  cil=(q*8)/KP, dwo=((q*8)%KP)/2.
// IN_FP32: loadB reads float2 from the raw input and converts (clamped so the
// only polluted values feed zero-weight padded taps / t>=Tout lanes).
// POOL: AvgPool2+ReLU fused via shfl_xor(1) pair-average.
// ---------------------------------------------------------------------------
template<int KP, int CI, int NBLK, bool IN_FP32, bool RELU, bool OUT_F16, bool POOL>
__global__ __launch_bounds__(256)
void conv_mfma9(const unsigned short* __restrict__ xh,
                const unsigned short* __restrict__ wpk,
                const float* __restrict__ bias,
                unsigned short* __restrict__ yh,
                float* __restrict__ yf,
                int Tin, int Tout)
{
    constexpr int CO    = 96;
    constexpr int STEPS = CI * KP / 32;
    constexpr int NCI   = 32 / KP;
    constexpr int RD    = NBLK + KP / 2 + 2;
    constexpr int NTW   = NBLK / 64;
    constexpr int TOT   = NCI * RD;
    constexpr int NIT   = (TOT + 255) / 256;

    __shared__ __align__(16) unsigned short As[2][6144];   // 24 KB A dbuf
    __shared__ unsigned int Bs[2][TOT];                    // B dbuf (fp16 pairs)

    const int tid  = threadIdx.x;
    const int lane = tid & 63;
    const int wave = tid >> 6;
    const int quad = lane >> 4;
    const int l16  = lane & 15;
    const int wc0  = wave * (NBLK / 4);

    const int nT = (Tout + NBLK - 1) / NBLK;
    const int b  = blockIdx.x / nT;
    const int t0 = (blockIdx.x % nT) * NBLK;

    const float* xf = (const float*)xh;
    const unsigned int* xb = (const unsigned int*)xh + (((size_t)b * CI * Tin) >> 1);
    const int rowd = Tin >> 1;

    auto stageA = [&](int s, int buf) {
        const char* g = (const char*)(wpk + (size_t)s * 6144) + (size_t)lane * 16;
        char* l = (char*)&As[buf][0] + (size_t)lane * 16;
        #pragma unroll
        for (int i = 0; i < 3; ++i) {
            int seg = i * 4 + wave;
            stage16(g + seg * 1024, l + seg * 1024);
        }
    };

    unsigned int breg[NIT];
    auto loadB = [&](int s) {
        const int ci0 = s * NCI;
        #pragma unroll
        for (int it = 0; it < NIT; ++it) {
            int i = tid + it * 256;
            if (i < TOT) {
                int r = i / RD, d = i - r * RD;        // RD constexpr
                if (IN_FP32) {
                    int e = 2 * (t0 + d);
                    if (e > Tin - 2) e = Tin - 2;      // clamp: padded-tap/t>=Tout only
                    const float* src = xf + ((size_t)b * CI + ci0 + r) * Tin + e;
                    float2 v = *(const float2*)src;
                    breg[it] = (unsigned int)f2h_bits(v.x)
                             | ((unsigned int)f2h_bits(v.y) << 16);
                } else {
                    breg[it] = *(xb + (size_t)(ci0 + r) * rowd + t0 + d);
                }
            }
        }
    };
    auto storeB = [&](int buf) {
        #pragma unroll
        for (int it = 0; it < NIT; ++it) {
            int i = tid + it * 256;
            if (i < TOT) Bs[buf][i] = breg[it];
        }
    };

    f32x4 acc[6][NTW];
    #pragma unroll
    for (int mt = 0; mt < 6; ++mt)
        #pragma unroll
        for (int nt = 0; nt < NTW; ++nt) acc[mt][nt] = (f32x4)0.f;

    const int cil = (quad * 8) / KP;
    const int dwo = ((quad * 8) % KP) >> 1;

    loadB(0); storeB(0); stageA(0, 0);
    __syncthreads();

    for (int s = 0; s < STEPS; ++s) {
        const int buf = s & 1;

        if (s + 1 < STEPS) {
            loadB(s + 1);               // global loads in flight during MFMAs
            stageA(s + 1, buf ^ 1);
        }

        f16x8 Ah[6], Al[6];
        #pragma unroll
        for (int mt = 0; mt < 6; ++mt) {
            Ah[mt] = *(const f16x8*)&As[buf][(mt) * 512 + lane * 8];
            Al[mt] = *(const f16x8*)&As[buf][(6 + mt) * 512 + lane * 8];
        }
        const unsigned int* bp = &Bs[buf][cil * RD + wc0 + l16 + dwo];
        #pragma unroll
        for (int nt = 0; nt < NTW; ++nt) {
            union { unsigned int u[4]; f16x8 v; } Bv;
            #pragma unroll
            for (int p = 0; p < 4; ++p) Bv.u[p] = bp[nt * 16 + p];
            #pragma unroll
            for (int mt = 0; mt < 6; ++mt)
                acc[mt][nt] = __builtin_amdgcn_mfma_f32_16x16x32_f16(Ah[mt], Bv.v, acc[mt][nt], 0, 0, 0);
            #pragma unroll
            for (int mt = 0; mt < 6; ++mt)
                acc[mt][nt] = __builtin_amdgcn_mfma_f32_16x16x32_f16(Al[mt], Bv.v, acc[mt][nt], 0, 0, 0);
        }

        if (s + 1 < STEPS) storeB(buf ^ 1);
        __syncthreads();
    }

    // epilogue: C/D layout col=l16 (t), row = quad*4+reg
    #pragma unroll
    for (int mt = 0; mt < 6; ++mt) {
        #pragma unroll
        for (int r = 0; r < 4; ++r) {
            int o = mt * 16 + quad * 4 + r;
            float bv = bias[o];
            #pragma unroll
            for (int nt = 0; nt < NTW; ++nt) {
                int t = t0 + wc0 + nt * 16 + l16;
                float v = acc[mt][nt][r] + bv;
                if (RELU) v = fmaxf(v, 0.f);
                if (POOL) {
                    float sum = v + __shfl_xor(v, 1, 64);
                    if ((lane & 1) == 0 && t + 1 < Tout) {
                        float pr = fmaxf(0.5f * sum, 0.f);
                        size_t pidx = ((size_t)b * CO + o) * (Tout >> 1) + (t >> 1);
                        if (OUT_F16) yh[pidx] = f2h_bits(pr);
                        else         yf[pidx] = pr;
                    }
                } else if (t < Tout) {
                    size_t oidx = ((size_t)b * CO + o) * Tout + t;
                    if (OUT_F16) yh[oidx] = f2h_bits(v);
                    else         yf[oidx] = v;
                }
            }
        }
    }
}

// ---------------------------------------------------------------------------
// single repack kernel: 5 MFMA A-images (fp16 hi/lo) + 2 fp32 [ci][k][o]
// ---------------------------------------------------------------------------
__device__ __forceinline__ void repack_img(const float* __restrict__ w,
                                           unsigned short* __restrict__ wpk,
                                           int idx, int KP, int KW, int CI)
{
    int j = idx & 7, lane = (idx >> 3) & 63, g = idx >> 9;
    int c = g / 24, r = g % 24;
    int mt = r % 6, sh = r / 6;
    int half = sh & 1, s = sh >> 1;
    int S  = c * 2 + s;
    int kg = S * 32 + (lane >> 4) * 8 + j;
    int o  = mt * 16 + (lane & 15);
    int ci = kg / KP, k = kg % KP;
    float val = (k < KW) ? w[((size_t)o * CI + ci) * KW + k] : 0.f;
    _Float16 hh = (_Float16)val;
    union { _Float16 h; unsigned short u; } cv;
    cv.h = (half == 0) ? hh : (_Float16)(val - (float)hh);
    wpk[idx] = cv.u;
}
__device__ __forceinline__ void repack_okc(const float* __restrict__ w,
                                           float* __restrict__ wr,
                                           int idx, int CI, int K, int CO)
{
    int o = idx % CO; int rem = idx / CO; int k = rem % K; int ci = rem / K;
    wr[idx] = w[((size_t)o * CI + ci) * K + k];
}

__global__ void repack_all(const float* w1, const float* w2, const float* w3,
                           const float* w4, const float* w5, const float* w6,
                           const float* w7,
                           unsigned short* p1, unsigned short* p2,
                           unsigned short* p3, unsigned short* p4,
                           unsigned short* p5, float* r6, float* r7)
{
    int idx = blockIdx.x * 256 + threadIdx.x;
    if (idx < 122880) { repack_img(w1, p1, idx, 16, 10, 40); return; }
    idx -= 122880;
    if (idx < 147456) { repack_img(w2, p2, idx, 8, 5, 96); return; }
    idx -= 147456;
    if (idx < 147456) { repack_img(w3, p3, idx, 8, 5, 96); return; }
    idx -= 147456;
    if (idx < 147456) { repack_img(w4, p4, idx, 8, 5, 96); return; }
    idx -= 147456;
    if (idx < 147456) { repack_img(w5, p5, idx, 8, 5, 96); return; }
    idx -= 147456;
    if (idx < 46080)  { repack_okc(w6, r6, idx, 96, 5, 96); return; }
    idx -= 46080;
    if (idx < 36864)  { repack_okc(w7, r7, idx, 96, 3, 128); return; }
}

// ---------------------------------------------------------------------------
// conv6: 96->96, K=5, s=2, 62->29, relu.  Grid 256 = 64 samples x 4 o-blocks.
// Wave-uniform weight reads (s_load); input LDS-resident.
// ---------------------------------------------------------------------------
__global__ __launch_bounds__(256)
void conv6_k(const float* __restrict__ y5p, const float* __restrict__ w6r,
             const float* __restrict__ b6, float* __restrict__ y6)
{
    __shared__ float s5[96 * 62];
    const int b = blockIdx.x >> 2, ob = blockIdx.x & 3;
    const int tid = threadIdx.x;
    for (int i = tid; i < 96 * 62; i += 256) s5[i] = y5p[(size_t)b * 96 * 62 + i];
    __syncthreads();

    const int wave = __builtin_amdgcn_readfirstlane(tid >> 6);
    const int t = tid & 63;
    if (t < 29) {
        const int o0 = ob * 24 + wave * 6;
        float a[6];
        #pragma unroll
        for (int oo = 0; oo < 6; oo++) a[oo] = 0.f;
        for (int ci = 0; ci < 96; ci++) {
            float xr[5];
            #pragma unroll
            for (int k = 0; k < 5; k++) xr[k] = s5[ci * 62 + 2 * t + k];
            #pragma unroll
            for (int k = 0; k < 5; k++) {
                const float* wp = w6r + (ci * 5 + k) * 96 + o0;   // wave-uniform
                #pragma unroll
                for (int oo = 0; oo < 6; oo++)
                    a[oo] = fmaf(wp[oo], xr[k], a[oo]);
            }
        }
        #pragma unroll
        for (int oo = 0; oo < 6; oo++)
            y6[((size_t)b * 96 + o0 + oo) * 29 + t] = fmaxf(a[oo] + b6[o0 + oo], 0.f);
    }
}

// ---------------------------------------------------------------------------
// tail2: conv7 (96->128, K=3, s=2, 29->14, relu) + masked max + MLP head.
// Grid 64.  conv7 splits ci across lane sub-quads (24 each), butterfly
// shfl_xor(16,32) reduction -> all 64 lanes busy.
// ---------------------------------------------------------------------------
__global__ __launch_bounds__(256)
void tail2(const float* __restrict__ y6,
           const float* __restrict__ w7r, const float* __restrict__ b7,
           const int* __restrict__ lens,
           const float* __restrict__ lw1, const float* __restrict__ lb1,
           const float* __restrict__ lw2, const float* __restrict__ lb2,
           const float* __restrict__ lw3, const float* __restrict__ lb3,
           float* __restrict__ out)
{
    __shared__ float s6[96 * 29 + 8];     // +8: benign overread slack (tl>=14)
    __shared__ float s7[128 * 14];
    __shared__ float feat[128], h1[128], h2[64];

    const int b = blockIdx.x, tid = threadIdx.x;
    for (int i = tid; i < 96 * 29; i += 256) s6[i] = y6[(size_t)b * 96 * 29 + i];
    __syncthreads();

    const int wave = __builtin_amdgcn_readfirstlane(tid >> 6);
    const int lane = tid & 63;
    const int sub  = lane >> 4;           // ci quarter
    const int tl   = lane & 15;           // t (active tl<14)
    {
        float a[32];
        #pragma unroll
        for (int oo = 0; oo < 32; oo++) a[oo] = 0.f;
        const int ci0 = sub * 24;
        for (int ci = ci0; ci < ci0 + 24; ci++) {
            float xr[3];
            #pragma unroll
            for (int k = 0; k < 3; k++) xr[k] = s6[ci * 29 + 2 * tl + k];
            #pragma unroll
            for (int k = 0; k < 3; k++) {
                const float* wp = w7r + (ci * 3 + k) * 128 + wave * 32;  // uniform
                #pragma unroll
                for (int oo = 0; oo < 32; oo++)
                    a[oo] = fmaf(wp[oo], xr[k], a[oo]);
            }
        }
        #pragma unroll
        for (int oo = 0; oo < 32; oo++) {
            float v = a[oo];
            v += __shfl_xor(v, 16, 64);   // sub 0<->1, 2<->3 (same tl)
            v += __shfl_xor(v, 32, 64);   // sub 0<->2
            if (sub == 0 && tl < 14) {
                int o = wave * 32 + oo;
                s7[o * 14 + tl] = fmaxf(v + b7[o], 0.f);
            }
        }
    }
    __syncthreads();

    if (tid < 128) {
        int L = lens[b];
        L = (L - 10) / 2 + 1;
        L = (L - 5) / 2 + 1;
        L = (L - 5) / 2 + 1;
        L = (L - 5) / 2 + 1;
        L = L / 2;
        L = (L - 5) / 2 + 1;
        L = L / 2;
        L = (L - 5) / 2 + 1;
        L = (L - 3) / 2 + 1;
        float m = -INFINITY;
        for (int t = 0; t < L; t++) m = fmaxf(m, s7[tid * 14 + t]);
        feat[tid] = m;
    }
    __syncthreads();

    if (tid < 128) {
        float s = lb1[tid];
        for (int i = 0; i < 128; i++) s = fmaf(lw1[tid * 128 + i], feat[i], s);
        h1[tid] = fmaxf(s, 0.f);
    }
    __syncthreads();
    if (tid < 64) {
        float s = lb2[tid];
        for (int i = 0; i < 128; i++) s = fmaf(lw2[tid * 128 + i], h1[i], s);
        h2[tid] = fmaxf(s, 0.f);
    }
    __syncthreads();
    if (tid < 5) {
        float s = lb3[tid];
        for (int i = 0; i < 64; i++) s = fmaf(lw3[tid * 64 + i], h2[i], s);
        out[b * 5 + tid] = s;
    }
}

extern "C" void kernel_launch(void* const* d_in, const int* in_sizes, int n_in,
                              void* d_out, int out_size, void* d_ws, size_t ws_size,
                              hipStream_t stream)
{
    const float* x    = (const float*)d_in[0];
    const int*   lens = (const int*)  d_in[1];
    const float* w1 = (const float*)d_in[2];   const float* b1 = (const float*)d_in[3];
    const float* w2 = (const float*)d_in[4];   const float* b2 = (const float*)d_in[5];
    const float* w3 = (const float*)d_in[6];   const float* b3 = (const float*)d_in[7];
    const float* w4 = (const float*)d_in[8];   const float* b4 = (const float*)d_in[9];
    const float* w5 = (const float*)d_in[10];  const float* b5 = (const float*)d_in[11];
    const float* w6 = (const float*)d_in[12];  const float* b6 = (const float*)d_in[13];
    const float* w7 = (const float*)d_in[14];  const float* b7 = (const float*)d_in[15];
    const float* lw1 = (const float*)d_in[16]; const float* lb1 = (const float*)d_in[17];
    const float* lw2 = (const float*)d_in[18]; const float* lb2 = (const float*)d_in[19];
    const float* lw3 = (const float*)d_in[20]; const float* lb3 = (const float*)d_in[21];
    float* out = (float*)d_out;
    char*  W   = (char*)d_ws;

    // lengths: 8192 -> 4092 -> 2044 -> 1020 -> 508 -> 254 -> 125 -> 62 -> 29 -> 14
    size_t off = 0;
    auto take = [&](size_t bytes) {
        size_t o = off; off = (off + bytes + 255) & ~(size_t)255; return o;
    };
    size_t o_y3h = take(((size_t)64 * 96 * 1020 + 2048) * 2);
    size_t o_y4h = take(((size_t)64 * 96 * 254 + 2048) * 2);   // fp16 pooled
    size_t o_y5p = take((size_t)64 * 96 * 62 * 4 + 1024);      // fp32 pooled
    size_t o_y6  = take((size_t)64 * 96 * 29 * 4);
    size_t o_wp1 = take((size_t)122880 * 2);
    size_t o_wp2 = take((size_t)147456 * 2);
    size_t o_wp3 = take((size_t)147456 * 2);
    size_t o_wp4 = take((size_t)147456 * 2);
    size_t o_wp5 = take((size_t)147456 * 2);
    size_t o_w6r = take((size_t)46080 * 4);
    size_t o_w7r = take((size_t)36864 * 4);
    size_t persist = off;

    auto chunk_bytes = [&](int Bc) -> size_t {
        size_t s = 0;
        s += ((size_t)Bc * 96 * 4092 + 2048) * 2 + 256;
        s += ((size_t)Bc * 96 * 2044 + 2048) * 2 + 256;
        return s;
    };
    int Bc = 64;
    while (Bc > 1 && persist + chunk_bytes(Bc) > ws_size) Bc >>= 1;
    size_t o_y1h = take(((size_t)Bc * 96 * 4092 + 2048) * 2);
    size_t o_y2h = take(((size_t)Bc * 96 * 2044 + 2048) * 2);

    auto US = [&](size_t o) { return (unsigned short*)(W + o); };
    auto FP = [&](size_t o) { return (float*)(W + o); };

    // one repack kernel (795648 elements)
    repack_all<<<dim3((795648 + 255) / 256), 256, 0, stream>>>(
        w1, w2, w3, w4, w5, w6, w7,
        US(o_wp1), US(o_wp2), US(o_wp3), US(o_wp4), US(o_wp5),
        FP(o_w6r), FP(o_w7r));

    const int nchunks = 64 / Bc;
    for (int c = 0; c < nchunks; c++) {
        const float* xc = x + (size_t)c * Bc * 40 * 8192;

        // conv1: fp32 in (fused convert), KP=16, NBLK=256 -> nT=16
        conv_mfma9<16, 40, 256, true, true, true, false><<<dim3(Bc * 16), 256, 0, stream>>>(
            (const unsigned short*)xc, US(o_wp1), b1, US(o_y1h), nullptr, 8192, 4092);
        // conv2: KP=8, NBLK=256 -> nT=8
        conv_mfma9< 8, 96, 256, false, true, true, false><<<dim3(Bc * 8), 256, 0, stream>>>(
            US(o_y1h), US(o_wp2), b2, US(o_y2h), nullptr, 4092, 2044);
        // conv3: KP=8, NBLK=128 -> nT=8
        unsigned short* y3h_c = US(o_y3h) + (size_t)c * Bc * 96 * 1020;
        conv_mfma9< 8, 96, 128, false, true, true, false><<<dim3(Bc * 8), 256, 0, stream>>>(
            US(o_y2h), US(o_wp3), b3, y3h_c, nullptr, 2044, 1020);
    }

    // conv4: NBLK=128 -> nT=4; fused AvgPool2+ReLU -> y4h (fp16, T=254)
    conv_mfma9<8, 96, 128, false, false, true, true><<<dim3(64 * 4), 256, 0, stream>>>(
        US(o_y3h), US(o_wp4), b4, US(o_y4h), nullptr, 1020, 508);

    // conv5 (MFMA): NBLK=64 -> nT=2; fused AvgPool2+ReLU -> y5p (fp32, T=62)
    conv_mfma9<8, 96, 64, false, false, false, true><<<dim3(64 * 2), 256, 0, stream>>>(
        US(o_y4h), US(o_wp5), b5, nullptr, FP(o_y5p), 254, 125);

    // conv6: grid 256 (64 samples x 4 o-blocks)
    conv6_k<<<dim3(256), 256, 0, stream>>>(FP(o_y5p), FP(o_w6r), b6, FP(o_y6));

    // conv7 + masked max + MLP head
    tail2<<<dim3(64), 256, 0, stream>>>(
        FP(o_y6), FP(o_w7r), b7, lens, lw1, lb1, lw2, lb2, lw3, lb3, out);
}